// Round 16
// baseline (166.532 us; speedup 1.0000x reference)
//
#include <hip/hip_runtime.h>
#include <math.h>

typedef unsigned short u16t;
typedef __attribute__((ext_vector_type(8))) __bf16 bf16x8;
typedef __attribute__((ext_vector_type(4))) float f32x4;
typedef __attribute__((ext_vector_type(16))) float f32x16;
typedef __attribute__((ext_vector_type(4))) unsigned short u16x4;

__device__ __forceinline__ u16t f2bf(float f) {
  union { float f; unsigned u; } v; v.f = f;
  return (u16t)((v.u + 0x7FFFu + ((v.u >> 16) & 1u)) >> 16);
}
__device__ __forceinline__ float bf2f(u16t u) {
  union { unsigned u; float f; } v; v.u = (unsigned)u << 16; return v.f;
}

// async global->LDS, 16B per lane; LDS dest linear (wave-uniform base + lane*16)
__device__ __forceinline__ void gload_lds16(const void* g, void* l) {
  __builtin_amdgcn_global_load_lds(
      (__attribute__((address_space(1))) void*)(uintptr_t)g,
      (__attribute__((address_space(3))) void*)(unsigned)(uintptr_t)l,
      16, 0, 0);
}

__device__ __forceinline__ f32x16 mf32(bf16x8 a, bf16x8 b, f32x16 c) {
  return __builtin_amdgcn_mfma_f32_32x32x16_bf16(a, b, c, 0, 0, 0);
}

// pack 8 f32 (2x f32x4) -> bf16x8 via v_cvt_pk_bf16_f32
__device__ __forceinline__ bf16x8 pk8(f32x4 a, f32x4 b) {
  union { unsigned u[4]; bf16x8 v; } r;
  asm("v_cvt_pk_bf16_f32 %0, %1, %2" : "=v"(r.u[0]) : "v"(a[0]), "v"(a[1]));
  asm("v_cvt_pk_bf16_f32 %0, %1, %2" : "=v"(r.u[1]) : "v"(a[2]), "v"(a[3]));
  asm("v_cvt_pk_bf16_f32 %0, %1, %2" : "=v"(r.u[2]) : "v"(b[0]), "v"(b[1]));
  asm("v_cvt_pk_bf16_f32 %0, %1, %2" : "=v"(r.u[3]) : "v"(b[2]), "v"(b[3]));
  return r.v;
}

// ---------------- fused 4x weight transpose f32[1024][1024] -> bf16 transposed ----
__global__ __launch_bounds__(256) void k_wtrans4(const float* __restrict__ Wq,
                                                 const float* __restrict__ Wk,
                                                 const float* __restrict__ Wv,
                                                 const float* __restrict__ Wo,
                                                 u16t* __restrict__ dstAll) {
  __shared__ u16t tile[64][68];
  int z = blockIdx.z;
  const float* in = z == 0 ? Wq : z == 1 ? Wk : z == 2 ? Wv : Wo;
  u16t* out = dstAll + ((size_t)z << 20);
  int r0 = blockIdx.y * 64, c0 = blockIdx.x * 64;
  int t = threadIdx.x;
  int rr = t >> 4, q4 = (t & 15) * 4;
#pragma unroll
  for (int i = 0; i < 4; i++) {
    int r = rr + i * 16;
    f32x4 x = *reinterpret_cast<const f32x4*>(&in[(size_t)(r0 + r) * 1024 + c0 + q4]);
#pragma unroll
    for (int j = 0; j < 4; j++) tile[r][q4 + j] = f2bf(x[j]);
  }
  __syncthreads();
#pragma unroll
  for (int i = 0; i < 4; i++) {
    int c = rr + i * 16;
    u16x4 y;
#pragma unroll
    for (int j = 0; j < 4; j++) y[j] = tile[q4 + j][c];
    *reinterpret_cast<u16x4*>(&out[(size_t)(c0 + c) * 1024 + r0 + q4]) = y;
  }
}

// ---------------- dual bf16 transpose [2048][1024] -> [1024][2048]: kn->knT, vbf->vT ----
__global__ __launch_bounds__(256) void k_vtrans2(const u16t* __restrict__ in0,
                                                 const u16t* __restrict__ in1,
                                                 u16t* __restrict__ o0,
                                                 u16t* __restrict__ o1) {
  __shared__ u16t tile[64][68];
  int z = blockIdx.z;
  const u16t* in = z ? in1 : in0;
  u16t* out = z ? o1 : o0;
  int r0 = blockIdx.y * 64, c0 = blockIdx.x * 64;
  int t = threadIdx.x;
  int rr = t >> 4, q4 = (t & 15) * 4;
#pragma unroll
  for (int i = 0; i < 4; i++) {
    int r = rr + i * 16;
    u16x4 x = *reinterpret_cast<const u16x4*>(&in[(size_t)(r0 + r) * 1024 + c0 + q4]);
#pragma unroll
    for (int j = 0; j < 4; j++) tile[r][q4 + j] = x[j];
  }
  __syncthreads();
#pragma unroll
  for (int i = 0; i < 4; i++) {
    int c = rr + i * 16;
    u16x4 y;
#pragma unroll
    for (int j = 0; j < 4; j++) y[j] = tile[q4 + j][c];
    *reinterpret_cast<u16x4*>(&out[(size_t)(c0 + c) * 2048 + r0 + q4]) = y;
  }
}

// ---------------- column sums of kn and vbf -> f32[1024] each ----------------
__global__ __launch_bounds__(256) void k_colsum2(const u16t* __restrict__ kn,
                                                 const u16t* __restrict__ vb,
                                                 float* __restrict__ Kcol,
                                                 float* __restrict__ Vcol) {
  int t = threadIdx.x, c4 = t * 4, r0 = blockIdx.x * 32;
  float sk[4] = {0.f, 0.f, 0.f, 0.f}, sv[4] = {0.f, 0.f, 0.f, 0.f};
  for (int r = r0; r < r0 + 32; r++) {
    u16x4 a = *reinterpret_cast<const u16x4*>(&kn[((size_t)r << 10) + c4]);
    u16x4 b = *reinterpret_cast<const u16x4*>(&vb[((size_t)r << 10) + c4]);
#pragma unroll
    for (int j = 0; j < 4; j++) { sk[j] += bf2f(a[j]); sv[j] += bf2f(b[j]); }
  }
#pragma unroll
  for (int j = 0; j < 4; j++) {
    atomicAdd(&Kcol[c4 + j], sk[j]);
    atomicAdd(&Vcol[c4 + j], sv[j]);
  }
}

// ---------------- k_ktv: per-head M_h = kn_h^T @ v_h  (stored transposed, bf16) ----
__global__ __launch_bounds__(256) void k_ktv(const u16t* __restrict__ knT,
                                             const u16t* __restrict__ vT,
                                             const float* __restrict__ Kcol,
                                             u16t* __restrict__ MT) {
  __shared__ float sls[4][1024];
  int qd = blockIdx.x, h = blockIdx.y;
  int e1t = qd >> 1, e2t = qd & 1;
  int t = threadIdx.x, lane = t & 63, w = t >> 6;
  int l31 = lane & 31, hi = lane >> 5;
  const u16t* ap = knT + (((size_t)((h << 6) + e1t * 32 + l31)) << 11) + w * 512 + hi * 8;
  const u16t* bp = vT  + (((size_t)((h << 6) + e2t * 32 + l31)) << 11) + w * 512 + hi * 8;
  f32x16 acc = {};
#pragma unroll
  for (int k = 0; k < 32; k++) {
    bf16x8 a = *(const bf16x8*)(ap + k * 16);
    bf16x8 b = *(const bf16x8*)(bp + k * 16);
    acc = mf32(a, b, acc);
  }
#pragma unroll
  for (int r = 0; r < 16; r++) {
    int e1l = (r & 3) + 8 * (r >> 2) + 4 * hi;
    sls[w][e1l * 32 + l31] = acc[r];
  }
  __syncthreads();
#pragma unroll
  for (int i = 0; i < 4; i++) {
    int idx = t * 4 + i;
    int e1 = idx >> 5, e2 = idx & 31;
    float s = sls[0][idx] + sls[1][idx] + sls[2][idx] + sls[3][idx];
    MT[h * 4160 + (e2t * 32 + e2) * 64 + e1t * 32 + e1] = f2bf(s);
  }
  if (qd == 0 && t < 64)
    MT[h * 4160 + 4096 + t] = f2bf(Kcol[(h << 6) + t]);
}

// ---------------- k_ctx: ctx = (qn8 @ M + Vcol) / (2048 + qn8.Kcol) -> bf16 ----
__global__ __launch_bounds__(256) void k_ctx(const u16t* __restrict__ qn8,
                                             const u16t* __restrict__ MT,
                                             const float* __restrict__ Vcol,
                                             u16t* __restrict__ ctx) {
  int rt = blockIdx.x;
  int t = threadIdx.x, lane = t & 63, w = t >> 6;
  int l31 = lane & 31, hi = lane >> 5;
  int rowb = rt * 32;
  const u16t* qbase = qn8 + (((size_t)(rowb + l31)) << 10) + hi * 8;
  const f32x16 fz = {};
#pragma unroll
  for (int hh = 0; hh < 4; hh++) {
    int h = w * 4 + hh;
    const u16t* mbase = MT + h * 4160;
    bf16x8 af[4], kf[4];
#pragma unroll
    for (int ks = 0; ks < 4; ks++) {
      af[ks] = *(const bf16x8*)(qbase + (h << 6) + ks * 16);
      kf[ks] = *(const bf16x8*)(mbase + 4096 + ks * 16 + hi * 8);
    }
    f32x16 a0, a1, rd;
#pragma unroll
    for (int ks = 0; ks < 4; ks++) {
      bf16x8 b0 = *(const bf16x8*)(mbase + l31 * 64 + ks * 16 + hi * 8);
      bf16x8 b1 = *(const bf16x8*)(mbase + (32 + l31) * 64 + ks * 16 + hi * 8);
      a0 = mf32(af[ks], b0, ks ? a0 : fz);
      a1 = mf32(af[ks], b1, ks ? a1 : fz);
      rd = mf32(af[ks], kf[ks], ks ? rd : fz);
    }
    float vc0 = Vcol[(h << 6) + l31];
    float vc1 = Vcol[(h << 6) + 32 + l31];
#pragma unroll
    for (int r = 0; r < 16; r++) {
      int row = rowb + (r & 3) + 8 * (r >> 2) + 4 * hi;
      float ri = 1.f / (2048.f + rd[r]);
      u16t* cp = ctx + (((size_t)row) << 10) + (h << 6) + l31;
      cp[0]  = f2bf((a0[r] + vc0) * ri);
      cp[32] = f2bf((a1[r] + vc1) * ri);
    }
  }
}

// ---------------- QKV GEMM v3: 64x128 tile, A direct-from-global f32, B 3-buf DMA ----
// grid (8,128) = 1024 blocks; 4 waves; per-wave 32x64 (acc 2x4); 1 barrier/iter.
__global__ __launch_bounds__(256) void k_gemm_qkv(const float* __restrict__ target,
                                                  const float* __restrict__ source,
                                                  const float* __restrict__ value,
                                                  const u16t* __restrict__ Wt,
                                                  const float* __restrict__ b0,
                                                  const float* __restrict__ b1,
                                                  const float* __restrict__ b2,
                                                  u16t* __restrict__ out) {
  __shared__ __align__(16) u16t Bs[3][128 * 64];
  int bid = blockIdx.y * 8 + blockIdx.x;          // 1024 blocks
  int swz = (bid & 7) * 128 + (bid >> 3);         // XCD c -> 16 row-tiles x 8 col-tiles
  int n0 = (swz & 7) * 128;
  int m0 = (swz >> 3) * 64;
  int seg = (m0 >= 6144) ? 2 : (m0 >= 4096) ? 1 : 0;
  const float* bias = (seg == 0) ? b0 : (seg == 1) ? b1 : b2;
  const float* Af = (seg == 0) ? target : (seg == 1) ? source : value;
  int mloc = m0 - ((seg == 0) ? 0 : (seg == 1) ? 4096 : 6144);
  const u16t* Bseg = Wt + ((size_t)seg << 20);

  int t = threadIdx.x, lane = t & 63, w = t >> 6;
  int l15 = lane & 15, l16 = lane >> 4;
  int wr = w >> 1, wc = w & 1;
  f32x4 acc[2][4] = {};

#define QBDMA(KT, NB) do {                                                       \
    _Pragma("unroll")                                                            \
    for (int i = 0; i < 4; i++) {                                                \
      int idx_ = t + i * 256;                                                    \
      int row_ = idx_ >> 3;                                                      \
      int sc_ = (((idx_ & 7) ^ (row_ & 7)) << 3);                                \
      gload_lds16(Bseg + ((size_t)(n0 + row_) << 10) + (KT) + sc_,               \
                  (char*)Bs[NB] + idx_ * 16);                                    \
    } } while (0)

  QBDMA(0, 0);
  QBDMA(64, 1);
  asm volatile("s_waitcnt vmcnt(4)" ::: "memory");
  __builtin_amdgcn_s_barrier();
  asm volatile("" ::: "memory");

  int arow0 = mloc + wr * 32 + l15;
  for (int ki = 0; ki < 16; ki++) {
    int cur = ki % 3;
    if (ki + 2 < 16) QBDMA((ki + 2) << 6, (ki + 2) % 3);
    int kt = ki << 6;
    const char* bb = (const char*)Bs[cur];
#pragma unroll
    for (int kk = 0; kk < 2; kk++) {
      int kof = kt + kk * 32 + l16 * 8;
      bf16x8 af[2];
#pragma unroll
      for (int m = 0; m < 2; m++) {
        const float* ap = Af + (((size_t)(arow0 + m * 16)) << 10) + kof;
        af[m] = pk8(*(const f32x4*)ap, *(const f32x4*)(ap + 4));
      }
#pragma unroll
      for (int n = 0; n < 4; n++) {
        int br = wc * 64 + n * 16 + l15;
        bf16x8 bf = *(const bf16x8*)(bb + br * 128 + ((kk * 64 + l16 * 16) ^ ((br & 7) << 4)));
#pragma unroll
        for (int m = 0; m < 2; m++)
          acc[m][n] = __builtin_amdgcn_mfma_f32_16x16x32_bf16(af[m], bf, acc[m][n], 0, 0, 0);
      }
    }
    if (ki + 2 < 16) asm volatile("s_waitcnt vmcnt(4)" ::: "memory");
    else             asm volatile("s_waitcnt vmcnt(0)" ::: "memory");
    __builtin_amdgcn_s_barrier();
    asm volatile("" ::: "memory");
  }
#undef QBDMA

  float bbv[4];
#pragma unroll
  for (int n = 0; n < 4; n++) bbv[n] = bias[n0 + wc * 64 + n * 16 + l15];
  if (seg < 2) {
    float scale0 = (seg == 0) ? 0.125f : 1.f;
#pragma unroll
    for (int m = 0; m < 2; m++) {
#pragma unroll
      for (int r = 0; r < 4; r++) {
        float e[4]; float ss = 0.f;
#pragma unroll
        for (int n = 0; n < 4; n++) {
          float x = acc[m][n][r] + bbv[n];
          e[n] = x > 0.f ? x : (__expf(x) - 1.f);
          ss += e[n] * e[n];
        }
        ss += __shfl_xor(ss, 1); ss += __shfl_xor(ss, 2);
        ss += __shfl_xor(ss, 4); ss += __shfl_xor(ss, 8);
        float rinv = rsqrtf(ss) * scale0;
        int row = m0 + wr * 32 + m * 16 + l16 * 4 + r;
#pragma unroll
        for (int n = 0; n < 4; n++)
          out[((size_t)row << 10) + n0 + wc * 64 + n * 16 + l15] = f2bf(e[n] * rinv);
      }
    }
  } else {
#pragma unroll
    for (int m = 0; m < 2; m++) {
      int row = m0 + wr * 32 + m * 16 + l16 * 4;
#pragma unroll
      for (int n = 0; n < 4; n++) {
        int col = n0 + wc * 64 + n * 16 + l15;
#pragma unroll
        for (int r = 0; r < 4; r++)
          out[((size_t)(row + r) << 10) + col] = f2bf(acc[m][n][r] + bbv[n]);
      }
    }
  }
}

// ---------------- 128x128x(K=1024) MFMA core (R14-proven): gload_lds both, vmcnt(8) ----
__device__ __forceinline__ void gemm128_acc(const u16t* __restrict__ A,
                                            const u16t* __restrict__ Bt,
                                            int m0, int n0, f32x4 acc[4][4]) {
  __shared__ __align__(16) u16t As[2][128 * 64];
  __shared__ __align__(16) u16t Bs[2][128 * 64];
  int t = threadIdx.x, lane = t & 63, w = t >> 6;
  int l15 = lane & 15, l16 = lane >> 4;
  int wr = w >> 1, wc = w & 1;
  int srow = t >> 3;
  int slc = ((t & 7) ^ (srow & 7)) << 3;

#define GSTAGE(KT, NB) do {                                                      \
    _Pragma("unroll")                                                            \
    for (int i = 0; i < 4; i++) {                                                \
      int row_ = srow + i * 32;                                                  \
      int c16_ = (t + i * 256) * 16;                                             \
      gload_lds16(A + ((size_t)(m0 + row_) << 10) + (KT) + slc, (char*)As[NB] + c16_); \
      gload_lds16(Bt + ((size_t)(n0 + row_) << 10) + (KT) + slc, (char*)Bs[NB] + c16_); \
    } } while (0)

  GSTAGE(0, 0);
  for (int ki = 0; ki < 16; ki++) {
    int cur = ki & 1;
    if (ki < 15) {
      GSTAGE((ki + 1) << 6, cur ^ 1);
      asm volatile("s_waitcnt vmcnt(8)" ::: "memory");
    } else {
      asm volatile("s_waitcnt vmcnt(0)" ::: "memory");
    }
    __builtin_amdgcn_s_barrier();
    asm volatile("" ::: "memory");
#pragma unroll
    for (int kk = 0; kk < 2; kk++) {
      bf16x8 af[4], bfr[4];
#pragma unroll
      for (int m = 0; m < 4; m++) {
        int ar = wr * 64 + m * 16 + l15;
        af[m] = *(const bf16x8*)((char*)As[cur] + ar * 128 + ((kk * 64 + l16 * 16) ^ ((ar & 7) << 4)));
      }
#pragma unroll
      for (int n = 0; n < 4; n++) {
        int br = wc * 64 + n * 16 + l15;
        bfr[n] = *(const bf16x8*)((char*)Bs[cur] + br * 128 + ((kk * 64 + l16 * 16) ^ ((br & 7) << 4)));
      }
#pragma unroll
      for (int m = 0; m < 4; m++)
#pragma unroll
        for (int n = 0; n < 4; n++)
          acc[m][n] = __builtin_amdgcn_mfma_f32_16x16x32_bf16(af[m], bfr[n], acc[m][n], 0, 0, 0);
    }
    __builtin_amdgcn_s_barrier();
    asm volatile("" ::: "memory");
  }
#undef GSTAGE
}

// O-projection GEMM with fused residual + LN-statistics epilogue -> bf16 H + row sums
__global__ __launch_bounds__(256) void k_gemm_o(const u16t* __restrict__ A,
                                                const u16t* __restrict__ Wt,
                                                const float* __restrict__ bias,
                                                const float* __restrict__ target,
                                                u16t* __restrict__ Hb,
                                                float* __restrict__ rsums) {
  int bid = blockIdx.y * 8 + blockIdx.x;          // 256 blocks
  int swz = (bid & 7) * 32 + (bid >> 3);          // XCD x -> rows [x*512,(x+1)*512)
  int n0 = (swz & 7) * 128, m0 = (swz >> 3) * 128;
  f32x4 acc[4][4] = {};
  gemm128_acc(A, Wt, m0, n0, acc);
  int t = threadIdx.x, lane = t & 63, w = t >> 6;
  int l15 = lane & 15, l16 = lane >> 4;
  int wr = w >> 1, wc = w & 1;
  float bb[4];
#pragma unroll
  for (int n = 0; n < 4; n++) bb[n] = bias[n0 + wc * 64 + n * 16 + l15];
#pragma unroll
  for (int m = 0; m < 4; m++) {
#pragma unroll
    for (int r = 0; r < 4; r++) {
      int row = m0 + wr * 64 + m * 16 + l16 * 4 + r;
      float s = 0.f, ss = 0.f;
      float xs[4];
#pragma unroll
      for (int n = 0; n < 4; n++) {
        int col = n0 + wc * 64 + n * 16 + l15;
        float x = acc[m][n][r] + bb[n] + target[((size_t)row << 10) + col];
        xs[n] = x; s += x; ss = fmaf(x, x, ss);
      }
#pragma unroll
      for (int n = 0; n < 4; n++)
        Hb[((size_t)row << 10) + n0 + wc * 64 + n * 16 + l15] = f2bf(xs[n]);
      s += __shfl_xor(s, 1); ss += __shfl_xor(ss, 1);
      s += __shfl_xor(s, 2); ss += __shfl_xor(ss, 2);
      s += __shfl_xor(s, 4); ss += __shfl_xor(ss, 4);
      s += __shfl_xor(s, 8); ss += __shfl_xor(ss, 8);
      if (l15 == 0) {
        atomicAdd(&rsums[row * 2], s);
        atomicAdd(&rsums[row * 2 + 1], ss);
      }
    }
  }
}

// ---------------- LayerNorm finalize: pure normalize from precomputed sums ----------------
__global__ __launch_bounds__(256) void k_out_ln(const u16t* __restrict__ Hb,
                                                const float* __restrict__ rsums,
                                                const float* __restrict__ g,
                                                const float* __restrict__ bb,
                                                float* __restrict__ out) {
  int row = blockIdx.x, t = threadIdx.x;
  u16x4 hx = *reinterpret_cast<const u16x4*>(Hb + ((size_t)row << 10) + t * 4);
  float s = rsums[row * 2], ss = rsums[row * 2 + 1];
  float mu = s * (1.f / 1024.f);
  float var = ss * (1.f / 1024.f) - mu * mu;
  float rsn = rsqrtf(var + 1e-12f);
  f32x4 gv = *reinterpret_cast<const f32x4*>(&g[t * 4]);
  f32x4 bv = *reinterpret_cast<const f32x4*>(&bb[t * 4]);
  f32x4 o;
#pragma unroll
  for (int j = 0; j < 4; j++) o[j] = (bf2f(hx[j]) - mu) * rsn * gv[j] + bv[j];
  *reinterpret_cast<f32x4*>(&out[(size_t)row * 1024 + t * 4]) = o;
}

extern "C" void kernel_launch(void* const* d_in, const int* in_sizes, int n_in,
                              void* d_out, int out_size, void* d_ws, size_t ws_size,
                              hipStream_t stream) {
  const float* target = (const float*)d_in[0];
  const float* source = (const float*)d_in[1];
  const float* value  = (const float*)d_in[2];
  const float* Wq = (const float*)d_in[3];
  const float* bq = (const float*)d_in[4];
  const float* Wk = (const float*)d_in[5];
  const float* bk = (const float*)d_in[6];
  const float* Wv = (const float*)d_in[7];
  const float* bvp = (const float*)d_in[8];
  const float* Wo = (const float*)d_in[9];
  const float* bo = (const float*)d_in[10];
  const float* lng = (const float*)d_in[11];
  const float* lnb = (const float*)d_in[12];
  float* out = (float*)d_out;
  char* ws = (char*)d_ws;
  const size_t MB = 1u << 20;

  u16t* ctxb  = (u16t*)ws;                        // [0,8) bf16 [4096][1024]
  u16t* Wt    = (u16t*)(ws + 16 * MB);            // [16,24) 4x transposed weights
  u16t* Wot   = Wt + ((size_t)3 << 20);
  u16t* qkvnb = (u16t*)(ws + 24 * MB);            // [24,40) qn8 | kn | vbf
  u16t* qnb   = qkvnb;
  u16t* knb   = qkvnb + ((size_t)4096 << 10);
  u16t* vbf   = qkvnb + ((size_t)6144 << 10);
  u16t* knT   = (u16t*)(ws + 40 * MB);            // [40,44)
  u16t* vTb   = (u16t*)(ws + 44 * MB);            // [44,48)
  u16t* Hb    = (u16t*)(ws + 48 * MB);            // [48,56)
  float* Kcolf = (float*)(ws + 64 * MB);
  float* Vcolf = Kcolf + 1024;
  u16t* MTb   = (u16t*)(Vcolf + 1024);
  float* rsums = (float*)(ws + 65 * MB);

  k_wtrans4<<<dim3(16, 16, 4), 256, 0, stream>>>(Wq, Wk, Wv, Wo, Wt);
  hipMemsetAsync(Kcolf, 0, 8192, stream);
  hipMemsetAsync(rsums, 0, 4096 * 2 * sizeof(float), stream);
  k_gemm_qkv<<<dim3(8, 128), 256, 0, stream>>>(target, source, value, Wt, bq, bk, bvp, qkvnb);
  k_colsum2<<<dim3(64), 256, 0, stream>>>(knb, vbf, Kcolf, Vcolf);
  k_vtrans2<<<dim3(16, 32, 2), 256, 0, stream>>>(knb, vbf, knT, vTb);
  k_ktv<<<dim3(4, 16), 256, 0, stream>>>(knT, vTb, Kcolf, MTb);
  k_ctx<<<dim3(128), 256, 0, stream>>>(qnb, MTb, Vcolf, ctxb);
  k_gemm_o<<<dim3(8, 32), 256, 0, stream>>>(ctxb, Wot, bo, target, Hb, rsums);
  k_out_ln<<<dim3(4096), 256, 0, stream>>>(Hb, rsums, lng, lnb, out);
}

// Round 17
// 102.882 us; speedup vs baseline: 1.6187x; 1.6187x over previous
//
#include <hip/hip_runtime.h>
#include <math.h>

typedef unsigned short u16t;
typedef __attribute__((ext_vector_type(8))) __bf16 bf16x8;
typedef __attribute__((ext_vector_type(4))) float f32x4;
typedef __attribute__((ext_vector_type(16))) float f32x16;
typedef __attribute__((ext_vector_type(4))) unsigned short u16x4;

__device__ __forceinline__ u16t f2bf(float f) {
  union { float f; unsigned u; } v; v.f = f;
  return (u16t)((v.u + 0x7FFFu + ((v.u >> 16) & 1u)) >> 16);
}
__device__ __forceinline__ float bf2f(u16t u) {
  union { unsigned u; float f; } v; v.u = (unsigned)u << 16; return v.f;
}

// async global->LDS, 16B per lane; LDS dest linear (wave-uniform base + lane*16)
__device__ __forceinline__ void gload_lds16(const void* g, void* l) {
  __builtin_amdgcn_global_load_lds(
      (__attribute__((address_space(1))) void*)(uintptr_t)g,
      (__attribute__((address_space(3))) void*)(unsigned)(uintptr_t)l,
      16, 0, 0);
}

__device__ __forceinline__ f32x16 mf32(bf16x8 a, bf16x8 b, f32x16 c) {
  return __builtin_amdgcn_mfma_f32_32x32x16_bf16(a, b, c, 0, 0, 0);
}

// ---------------- fused f32 -> bf16 convert of target|source|value ----------------
__global__ __launch_bounds__(256) void k_cvt3(const float* __restrict__ t0,
                                              const float* __restrict__ s0,
                                              const float* __restrict__ v0,
                                              u16t* __restrict__ out) {
  int row = blockIdx.x, t = threadIdx.x;
  const float* src = row < 4096 ? t0 + ((size_t)row << 10)
                   : row < 6144 ? s0 + ((size_t)(row - 4096) << 10)
                                : v0 + ((size_t)(row - 6144) << 10);
  f32x4 x = *reinterpret_cast<const f32x4*>(src + t * 4);
  u16x4 y;
#pragma unroll
  for (int j = 0; j < 4; j++) y[j] = f2bf(x[j]);
  *reinterpret_cast<u16x4*>(out + ((size_t)row << 10) + t * 4) = y;
}

// ---------------- fused 4x weight transpose f32[1024][1024] -> bf16 transposed ----
__global__ __launch_bounds__(256) void k_wtrans4(const float* __restrict__ Wq,
                                                 const float* __restrict__ Wk,
                                                 const float* __restrict__ Wv,
                                                 const float* __restrict__ Wo,
                                                 u16t* __restrict__ dstAll) {
  __shared__ u16t tile[64][68];
  int z = blockIdx.z;
  const float* in = z == 0 ? Wq : z == 1 ? Wk : z == 2 ? Wv : Wo;
  u16t* out = dstAll + ((size_t)z << 20);
  int r0 = blockIdx.y * 64, c0 = blockIdx.x * 64;
  int t = threadIdx.x;
  int rr = t >> 4, q4 = (t & 15) * 4;
#pragma unroll
  for (int i = 0; i < 4; i++) {
    int r = rr + i * 16;
    f32x4 x = *reinterpret_cast<const f32x4*>(&in[(size_t)(r0 + r) * 1024 + c0 + q4]);
#pragma unroll
    for (int j = 0; j < 4; j++) tile[r][q4 + j] = f2bf(x[j]);
  }
  __syncthreads();
#pragma unroll
  for (int i = 0; i < 4; i++) {
    int c = rr + i * 16;
    u16x4 y;
#pragma unroll
    for (int j = 0; j < 4; j++) y[j] = tile[q4 + j][c];
    *reinterpret_cast<u16x4*>(&out[(size_t)(c0 + c) * 1024 + r0 + q4]) = y;
  }
}

// ---------------- dual bf16 transpose [2048][1024] -> [1024][2048]: kn->knT, vbf->vT ----
__global__ __launch_bounds__(256) void k_vtrans2(const u16t* __restrict__ in0,
                                                 const u16t* __restrict__ in1,
                                                 u16t* __restrict__ o0,
                                                 u16t* __restrict__ o1) {
  __shared__ u16t tile[64][68];
  int z = blockIdx.z;
  const u16t* in = z ? in1 : in0;
  u16t* out = z ? o1 : o0;
  int r0 = blockIdx.y * 64, c0 = blockIdx.x * 64;
  int t = threadIdx.x;
  int rr = t >> 4, q4 = (t & 15) * 4;
#pragma unroll
  for (int i = 0; i < 4; i++) {
    int r = rr + i * 16;
    u16x4 x = *reinterpret_cast<const u16x4*>(&in[(size_t)(r0 + r) * 1024 + c0 + q4]);
#pragma unroll
    for (int j = 0; j < 4; j++) tile[r][q4 + j] = x[j];
  }
  __syncthreads();
#pragma unroll
  for (int i = 0; i < 4; i++) {
    int c = rr + i * 16;
    u16x4 y;
#pragma unroll
    for (int j = 0; j < 4; j++) y[j] = tile[q4 + j][c];
    *reinterpret_cast<u16x4*>(&out[(size_t)(c0 + c) * 2048 + r0 + q4]) = y;
  }
}

// ---------------- column sums of kn and vbf -> f32[1024] each ----------------
__global__ __launch_bounds__(256) void k_colsum2(const u16t* __restrict__ kn,
                                                 const u16t* __restrict__ vb,
                                                 float* __restrict__ Kcol,
                                                 float* __restrict__ Vcol) {
  int t = threadIdx.x, c4 = t * 4, r0 = blockIdx.x * 32;
  float sk[4] = {0.f, 0.f, 0.f, 0.f}, sv[4] = {0.f, 0.f, 0.f, 0.f};
  for (int r = r0; r < r0 + 32; r++) {
    u16x4 a = *reinterpret_cast<const u16x4*>(&kn[((size_t)r << 10) + c4]);
    u16x4 b = *reinterpret_cast<const u16x4*>(&vb[((size_t)r << 10) + c4]);
#pragma unroll
    for (int j = 0; j < 4; j++) { sk[j] += bf2f(a[j]); sv[j] += bf2f(b[j]); }
  }
#pragma unroll
  for (int j = 0; j < 4; j++) {
    atomicAdd(&Kcol[c4 + j], sk[j]);
    atomicAdd(&Vcol[c4 + j], sv[j]);
  }
}

// ---------------- k_ktv: per-head M_h = kn_h^T @ v_h  (stored transposed, bf16) ----
__global__ __launch_bounds__(256) void k_ktv(const u16t* __restrict__ knT,
                                             const u16t* __restrict__ vT,
                                             const float* __restrict__ Kcol,
                                             u16t* __restrict__ MT) {
  __shared__ float sls[4][1024];
  int qd = blockIdx.x, h = blockIdx.y;
  int e1t = qd >> 1, e2t = qd & 1;
  int t = threadIdx.x, lane = t & 63, w = t >> 6;
  int l31 = lane & 31, hi = lane >> 5;
  const u16t* ap = knT + (((size_t)((h << 6) + e1t * 32 + l31)) << 11) + w * 512 + hi * 8;
  const u16t* bp = vT  + (((size_t)((h << 6) + e2t * 32 + l31)) << 11) + w * 512 + hi * 8;
  f32x16 acc = {};
#pragma unroll
  for (int k = 0; k < 32; k++) {
    bf16x8 a = *(const bf16x8*)(ap + k * 16);
    bf16x8 b = *(const bf16x8*)(bp + k * 16);
    acc = mf32(a, b, acc);
  }
#pragma unroll
  for (int r = 0; r < 16; r++) {
    int e1l = (r & 3) + 8 * (r >> 2) + 4 * hi;
    sls[w][e1l * 32 + l31] = acc[r];
  }
  __syncthreads();
#pragma unroll
  for (int i = 0; i < 4; i++) {
    int idx = t * 4 + i;
    int e1 = idx >> 5, e2 = idx & 31;
    float s = sls[0][idx] + sls[1][idx] + sls[2][idx] + sls[3][idx];
    MT[h * 4160 + (e2t * 32 + e2) * 64 + e1t * 32 + e1] = f2bf(s);
  }
  if (qd == 0 && t < 64)
    MT[h * 4160 + 4096 + t] = f2bf(Kcol[(h << 6) + t]);
}

// ---------------- k_ctx: ctx = (qn8 @ M + Vcol) / (2048 + qn8.Kcol) -> bf16 ----
__global__ __launch_bounds__(256) void k_ctx(const u16t* __restrict__ qn8,
                                             const u16t* __restrict__ MT,
                                             const float* __restrict__ Vcol,
                                             u16t* __restrict__ ctx) {
  int rt = blockIdx.x;
  int t = threadIdx.x, lane = t & 63, w = t >> 6;
  int l31 = lane & 31, hi = lane >> 5;
  int rowb = rt * 32;
  const u16t* qbase = qn8 + (((size_t)(rowb + l31)) << 10) + hi * 8;
  const f32x16 fz = {};
#pragma unroll
  for (int hh = 0; hh < 4; hh++) {
    int h = w * 4 + hh;
    const u16t* mbase = MT + h * 4160;
    bf16x8 af[4], kf[4];
#pragma unroll
    for (int ks = 0; ks < 4; ks++) {
      af[ks] = *(const bf16x8*)(qbase + (h << 6) + ks * 16);
      kf[ks] = *(const bf16x8*)(mbase + 4096 + ks * 16 + hi * 8);
    }
    f32x16 a0, a1, rd;
#pragma unroll
    for (int ks = 0; ks < 4; ks++) {
      bf16x8 b0 = *(const bf16x8*)(mbase + l31 * 64 + ks * 16 + hi * 8);
      bf16x8 b1 = *(const bf16x8*)(mbase + (32 + l31) * 64 + ks * 16 + hi * 8);
      a0 = mf32(af[ks], b0, ks ? a0 : fz);
      a1 = mf32(af[ks], b1, ks ? a1 : fz);
      rd = mf32(af[ks], kf[ks], ks ? rd : fz);
    }
    float vc0 = Vcol[(h << 6) + l31];
    float vc1 = Vcol[(h << 6) + 32 + l31];
#pragma unroll
    for (int r = 0; r < 16; r++) {
      int row = rowb + (r & 3) + 8 * (r >> 2) + 4 * hi;
      float ri = 1.f / (2048.f + rd[r]);
      u16t* cp = ctx + (((size_t)row) << 10) + (h << 6) + l31;
      cp[0]  = f2bf((a0[r] + vc0) * ri);
      cp[32] = f2bf((a1[r] + vc1) * ri);
    }
  }
}

// ---------------- 128x128x(K=1024) MFMA core, 512 threads (8 waves, 4x2) ----------------
// Dual gload_lds DMA (R14-proven), dbuf, vmcnt(8)... per-thread 4 loads/stage -> vmcnt(4).
// 16 waves/CU at 2 blocks/CU: double R14 TLP. acc[2][4] per wave (rows wr*32, cols wc*64).
__device__ __forceinline__ void gemm128_acc8(const u16t* __restrict__ A,
                                             const u16t* __restrict__ Bt,
                                             int m0, int n0, f32x4 acc[2][4]) {
  __shared__ __align__(16) u16t As[2][128 * 64];
  __shared__ __align__(16) u16t Bs[2][128 * 64];
  int t = threadIdx.x, lane = t & 63, w = t >> 6;
  int l15 = lane & 15, l16 = lane >> 4;
  int wr = w >> 1, wc = w & 1;
  int srow = t >> 3;                      // 0..63
  int slc = ((t & 7) ^ (srow & 7)) << 3;  // pre-swizzled element offset

#define GSTAGE(KT, NB) do {                                                      \
    _Pragma("unroll")                                                            \
    for (int i = 0; i < 2; i++) {                                                \
      int row_ = srow + i * 64;                                                  \
      int c16_ = (t + i * 512) * 16;                                             \
      gload_lds16(A + ((size_t)(m0 + row_) << 10) + (KT) + slc, (char*)As[NB] + c16_); \
      gload_lds16(Bt + ((size_t)(n0 + row_) << 10) + (KT) + slc, (char*)Bs[NB] + c16_); \
    } } while (0)

  GSTAGE(0, 0);
  for (int ki = 0; ki < 16; ki++) {
    int cur = ki & 1;
    if (ki < 15) {
      GSTAGE((ki + 1) << 6, cur ^ 1);
      asm volatile("s_waitcnt vmcnt(4)" ::: "memory");
    } else {
      asm volatile("s_waitcnt vmcnt(0)" ::: "memory");
    }
    __builtin_amdgcn_s_barrier();
    asm volatile("" ::: "memory");
#pragma unroll
    for (int kk = 0; kk < 2; kk++) {
      bf16x8 af[2], bfr[4];
#pragma unroll
      for (int m = 0; m < 2; m++) {
        int ar = wr * 32 + m * 16 + l15;
        af[m] = *(const bf16x8*)((char*)As[cur] + ar * 128 + ((kk * 64 + l16 * 16) ^ ((ar & 7) << 4)));
      }
#pragma unroll
      for (int n = 0; n < 4; n++) {
        int br = wc * 64 + n * 16 + l15;
        bfr[n] = *(const bf16x8*)((char*)Bs[cur] + br * 128 + ((kk * 64 + l16 * 16) ^ ((br & 7) << 4)));
      }
#pragma unroll
      for (int m = 0; m < 2; m++)
#pragma unroll
        for (int n = 0; n < 4; n++)
          acc[m][n] = __builtin_amdgcn_mfma_f32_16x16x32_bf16(af[m], bfr[n], acc[m][n], 0, 0, 0);
    }
    __builtin_amdgcn_s_barrier();
    asm volatile("" ::: "memory");
  }
#undef GSTAGE
}

// QKV GEMM (bf16 A) with fused bias + ELU + per-head L2-norm epilogue -> bf16
// XCD-swizzled; 512-thread blocks
__global__ __launch_bounds__(512) void k_gemm_qkv(const u16t* __restrict__ A,
                                                  const u16t* __restrict__ Wt,
                                                  const float* __restrict__ b0,
                                                  const float* __restrict__ b1,
                                                  const float* __restrict__ b2,
                                                  u16t* __restrict__ out) {
  int bid = blockIdx.y * 8 + blockIdx.x;          // 512 blocks
  int swz = (bid & 7) * 64 + (bid >> 3);          // bijective XCD chunking
  int n0 = (swz & 7) * 128, m0 = (swz >> 3) * 128;
  int seg = (m0 >= 6144) ? 2 : (m0 >= 4096) ? 1 : 0;
  const float* bias = (seg == 0) ? b0 : (seg == 1) ? b1 : b2;
  f32x4 acc[2][4] = {};
  gemm128_acc8(A, Wt + ((size_t)seg << 20), m0, n0, acc);

  int t = threadIdx.x, lane = t & 63, w = t >> 6;
  int l15 = lane & 15, l16 = lane >> 4;
  int wr = w >> 1, wc = w & 1;
  float bb[4];
#pragma unroll
  for (int n = 0; n < 4; n++) bb[n] = bias[n0 + wc * 64 + n * 16 + l15];
  if (seg < 2) {
    float scale0 = (seg == 0) ? 0.125f : 1.f;
#pragma unroll
    for (int m = 0; m < 2; m++) {
#pragma unroll
      for (int r = 0; r < 4; r++) {
        float e[4]; float ss = 0.f;
#pragma unroll
        for (int n = 0; n < 4; n++) {
          float x = acc[m][n][r] + bb[n];
          e[n] = x > 0.f ? x : (__expf(x) - 1.f);
          ss += e[n] * e[n];
        }
        ss += __shfl_xor(ss, 1); ss += __shfl_xor(ss, 2);
        ss += __shfl_xor(ss, 4); ss += __shfl_xor(ss, 8);
        float rinv = rsqrtf(ss) * scale0;
        int row = m0 + wr * 32 + m * 16 + l16 * 4 + r;
#pragma unroll
        for (int n = 0; n < 4; n++)
          out[((size_t)row << 10) + n0 + wc * 64 + n * 16 + l15] = f2bf(e[n] * rinv);
      }
    }
  } else {
#pragma unroll
    for (int m = 0; m < 2; m++) {
      int row = m0 + wr * 32 + m * 16 + l16 * 4;
#pragma unroll
      for (int n = 0; n < 4; n++) {
        int col = n0 + wc * 64 + n * 16 + l15;
#pragma unroll
        for (int r = 0; r < 4; r++)
          out[((size_t)(row + r) << 10) + col] = f2bf(acc[m][n][r] + bb[n]);
      }
    }
  }
}

// O-projection GEMM with fused residual + LN-statistics epilogue -> bf16 H + row sums
__global__ __launch_bounds__(512) void k_gemm_o(const u16t* __restrict__ A,
                                                const u16t* __restrict__ Wt,
                                                const float* __restrict__ bias,
                                                const float* __restrict__ target,
                                                u16t* __restrict__ Hb,
                                                float* __restrict__ rsums) {
  int bid = blockIdx.y * 8 + blockIdx.x;          // 256 blocks
  int swz = (bid & 7) * 32 + (bid >> 3);          // XCD chunking
  int n0 = (swz & 7) * 128, m0 = (swz >> 3) * 128;
  f32x4 acc[2][4] = {};
  gemm128_acc8(A, Wt, m0, n0, acc);
  int t = threadIdx.x, lane = t & 63, w = t >> 6;
  int l15 = lane & 15, l16 = lane >> 4;
  int wr = w >> 1, wc = w & 1;
  float bb[4];
#pragma unroll
  for (int n = 0; n < 4; n++) bb[n] = bias[n0 + wc * 64 + n * 16 + l15];
#pragma unroll
  for (int m = 0; m < 2; m++) {
#pragma unroll
    for (int r = 0; r < 4; r++) {
      int row = m0 + wr * 32 + m * 16 + l16 * 4 + r;
      float s = 0.f, ss = 0.f;
      float xs[4];
#pragma unroll
      for (int n = 0; n < 4; n++) {
        int col = n0 + wc * 64 + n * 16 + l15;
        float x = acc[m][n][r] + bb[n] + target[((size_t)row << 10) + col];
        xs[n] = x; s += x; ss = fmaf(x, x, ss);
      }
#pragma unroll
      for (int n = 0; n < 4; n++)
        Hb[((size_t)row << 10) + n0 + wc * 64 + n * 16 + l15] = f2bf(xs[n]);
      s += __shfl_xor(s, 1); ss += __shfl_xor(ss, 1);
      s += __shfl_xor(s, 2); ss += __shfl_xor(ss, 2);
      s += __shfl_xor(s, 4); ss += __shfl_xor(ss, 4);
      s += __shfl_xor(s, 8); ss += __shfl_xor(ss, 8);
      if (l15 == 0) {
        atomicAdd(&rsums[row * 2], s);
        atomicAdd(&rsums[row * 2 + 1], ss);
      }
    }
  }
}

// ---------------- LayerNorm finalize: pure normalize from precomputed sums ----------------
__global__ __launch_bounds__(256) void k_out_ln(const u16t* __restrict__ Hb,
                                                const float* __restrict__ rsums,
                                                const float* __restrict__ g,
                                                const float* __restrict__ bb,
                                                float* __restrict__ out) {
  int row = blockIdx.x, t = threadIdx.x;
  u16x4 hx = *reinterpret_cast<const u16x4*>(Hb + ((size_t)row << 10) + t * 4);
  float s = rsums[row * 2], ss = rsums[row * 2 + 1];
  float mu = s * (1.f / 1024.f);
  float var = ss * (1.f / 1024.f) - mu * mu;
  float rsn = rsqrtf(var + 1e-12f);
  f32x4 gv = *reinterpret_cast<const f32x4*>(&g[t * 4]);
  f32x4 bv = *reinterpret_cast<const f32x4*>(&bb[t * 4]);
  f32x4 o;
#pragma unroll
  for (int j = 0; j < 4; j++) o[j] = (bf2f(hx[j]) - mu) * rsn * gv[j] + bv[j];
  *reinterpret_cast<f32x4*>(&out[(size_t)row * 1024 + t * 4]) = o;
}

extern "C" void kernel_launch(void* const* d_in, const int* in_sizes, int n_in,
                              void* d_out, int out_size, void* d_ws, size_t ws_size,
                              hipStream_t stream) {
  const float* target = (const float*)d_in[0];
  const float* source = (const float*)d_in[1];
  const float* value  = (const float*)d_in[2];
  const float* Wq = (const float*)d_in[3];
  const float* bq = (const float*)d_in[4];
  const float* Wk = (const float*)d_in[5];
  const float* bk = (const float*)d_in[6];
  const float* Wv = (const float*)d_in[7];
  const float* bvp = (const float*)d_in[8];
  const float* Wo = (const float*)d_in[9];
  const float* bo = (const float*)d_in[10];
  const float* lng = (const float*)d_in[11];
  const float* lnb = (const float*)d_in[12];
  float* out = (float*)d_out;
  char* ws = (char*)d_ws;
  const size_t MB = 1u << 20;

  // ws layout (R10/R14-proven):
  //  [0,16)  abf bf16 [8192][1024] target|source|value (ctxb overlays [0,8) after qkv)
  //  [16,24) Wt bf16 4x transposed weights
  //  [24,40) qkvnb: qn8 | kn | vbf
  //  [40,44) knT  [44,48) vT  [48,56) Hb
  //  [64MB)  Kcol | Vcol | MT     [65MB) rsums
  u16t* abf   = (u16t*)ws;
  u16t* ctxb  = (u16t*)ws;
  u16t* Wt    = (u16t*)(ws + 16 * MB);
  u16t* Wot   = Wt + ((size_t)3 << 20);
  u16t* qkvnb = (u16t*)(ws + 24 * MB);
  u16t* qnb   = qkvnb;
  u16t* knb   = qkvnb + ((size_t)4096 << 10);
  u16t* vbf   = qkvnb + ((size_t)6144 << 10);
  u16t* knT   = (u16t*)(ws + 40 * MB);
  u16t* vTb   = (u16t*)(ws + 44 * MB);
  u16t* Hb    = (u16t*)(ws + 48 * MB);
  float* Kcolf = (float*)(ws + 64 * MB);
  float* Vcolf = Kcolf + 1024;
  u16t* MTb   = (u16t*)(Vcolf + 1024);
  float* rsums = (float*)(ws + 65 * MB);

  k_cvt3<<<dim3(8192), 256, 0, stream>>>(target, source, value, abf);
  k_wtrans4<<<dim3(16, 16, 4), 256, 0, stream>>>(Wq, Wk, Wv, Wo, Wt);
  hipMemsetAsync(Kcolf, 0, 8192, stream);
  hipMemsetAsync(rsums, 0, 4096 * 2 * sizeof(float), stream);
  k_gemm_qkv<<<dim3(8, 64), 512, 0, stream>>>(abf, Wt, bq, bk, bvp, qkvnb);
  k_colsum2<<<dim3(64), 256, 0, stream>>>(knb, vbf, Kcolf, Vcolf);
  k_vtrans2<<<dim3(16, 32, 2), 256, 0, stream>>>(knb, vbf, knT, vTb);
  k_ktv<<<dim3(4, 16), 256, 0, stream>>>(knT, vTb, Kcolf, MTb);
  k_ctx<<<dim3(128), 256, 0, stream>>>(qnb, MTb, Vcolf, ctxb);
  k_gemm_o<<<dim3(8, 32), 512, 0, stream>>>(ctxb, Wot, bo, target, Hb, rsums);
  k_out_ln<<<dim3(4096), 256, 0, stream>>>(Hb, rsums, lng, lnb, out);
}

// Round 18
// 99.153 us; speedup vs baseline: 1.6795x; 1.0376x over previous
//
#include <hip/hip_runtime.h>
#include <math.h>

typedef unsigned short u16t;
typedef __attribute__((ext_vector_type(8))) __bf16 bf16x8;
typedef __attribute__((ext_vector_type(4))) float f32x4;
typedef __attribute__((ext_vector_type(16))) float f32x16;
typedef __attribute__((ext_vector_type(4))) unsigned short u16x4;

__device__ __forceinline__ u16t f2bf(float f) {
  union { float f; unsigned u; } v; v.f = f;
  return (u16t)((v.u + 0x7FFFu + ((v.u >> 16) & 1u)) >> 16);
}
__device__ __forceinline__ float bf2f(u16t u) {
  union { unsigned u; float f; } v; v.u = (unsigned)u << 16; return v.f;
}

// async global->LDS, 16B per lane; LDS dest linear (wave-uniform base + lane*16)
__device__ __forceinline__ void gload_lds16(const void* g, void* l) {
  __builtin_amdgcn_global_load_lds(
      (__attribute__((address_space(1))) void*)(uintptr_t)g,
      (__attribute__((address_space(3))) void*)(unsigned)(uintptr_t)l,
      16, 0, 0);
}

__device__ __forceinline__ f32x16 mf32(bf16x8 a, bf16x8 b, f32x16 c) {
  return __builtin_amdgcn_mfma_f32_32x32x16_bf16(a, b, c, 0, 0, 0);
}

// ---------------- fused f32 -> bf16 convert of target|source|value ----------------
__global__ __launch_bounds__(256) void k_cvt3(const float* __restrict__ t0,
                                              const float* __restrict__ s0,
                                              const float* __restrict__ v0,
                                              u16t* __restrict__ out) {
  int row = blockIdx.x, t = threadIdx.x;
  const float* src = row < 4096 ? t0 + ((size_t)row << 10)
                   : row < 6144 ? s0 + ((size_t)(row - 4096) << 10)
                                : v0 + ((size_t)(row - 6144) << 10);
  f32x4 x = *reinterpret_cast<const f32x4*>(src + t * 4);
  u16x4 y;
#pragma unroll
  for (int j = 0; j < 4; j++) y[j] = f2bf(x[j]);
  *reinterpret_cast<u16x4*>(out + ((size_t)row << 10) + t * 4) = y;
}

// ---------------- fused 4x weight transpose + accumulator zeroing ----------------
// Also zeroes Kcol|Vcol (2048 f32, contiguous) and rsums (8192 f32) from y==0,z==0 blocks;
// stream order guarantees completion before any later-kernel atomicAdd.
__global__ __launch_bounds__(256) void k_wtrans4(const float* __restrict__ Wq,
                                                 const float* __restrict__ Wk,
                                                 const float* __restrict__ Wv,
                                                 const float* __restrict__ Wo,
                                                 u16t* __restrict__ dstAll,
                                                 float* __restrict__ KVcol,
                                                 float* __restrict__ rsums) {
  __shared__ u16t tile[64][68];
  int z = blockIdx.z;
  const float* in = z == 0 ? Wq : z == 1 ? Wk : z == 2 ? Wv : Wo;
  u16t* out = dstAll + ((size_t)z << 20);
  int r0 = blockIdx.y * 64, c0 = blockIdx.x * 64;
  int t = threadIdx.x;
  if (z == 0 && blockIdx.y == 0) {
    int g = blockIdx.x * 256 + t;          // 0..4095
    if (g < 2048) KVcol[g] = 0.f;
    rsums[g] = 0.f;
    rsums[g + 4096] = 0.f;
  }
  int rr = t >> 4, q4 = (t & 15) * 4;
#pragma unroll
  for (int i = 0; i < 4; i++) {
    int r = rr + i * 16;
    f32x4 x = *reinterpret_cast<const f32x4*>(&in[(size_t)(r0 + r) * 1024 + c0 + q4]);
#pragma unroll
    for (int j = 0; j < 4; j++) tile[r][q4 + j] = f2bf(x[j]);
  }
  __syncthreads();
#pragma unroll
  for (int i = 0; i < 4; i++) {
    int c = rr + i * 16;
    u16x4 y;
#pragma unroll
    for (int j = 0; j < 4; j++) y[j] = tile[q4 + j][c];
    *reinterpret_cast<u16x4*>(&out[(size_t)(c0 + c) * 1024 + r0 + q4]) = y;
  }
}

// ---------------- dual bf16 transpose [2048][1024] -> [1024][2048]: kn->knT, vbf->vT ----
__global__ __launch_bounds__(256) void k_vtrans2(const u16t* __restrict__ in0,
                                                 const u16t* __restrict__ in1,
                                                 u16t* __restrict__ o0,
                                                 u16t* __restrict__ o1) {
  __shared__ u16t tile[64][68];
  int z = blockIdx.z;
  const u16t* in = z ? in1 : in0;
  u16t* out = z ? o1 : o0;
  int r0 = blockIdx.y * 64, c0 = blockIdx.x * 64;
  int t = threadIdx.x;
  int rr = t >> 4, q4 = (t & 15) * 4;
#pragma unroll
  for (int i = 0; i < 4; i++) {
    int r = rr + i * 16;
    u16x4 x = *reinterpret_cast<const u16x4*>(&in[(size_t)(r0 + r) * 1024 + c0 + q4]);
#pragma unroll
    for (int j = 0; j < 4; j++) tile[r][q4 + j] = x[j];
  }
  __syncthreads();
#pragma unroll
  for (int i = 0; i < 4; i++) {
    int c = rr + i * 16;
    u16x4 y;
#pragma unroll
    for (int j = 0; j < 4; j++) y[j] = tile[q4 + j][c];
    *reinterpret_cast<u16x4*>(&out[(size_t)(c0 + c) * 2048 + r0 + q4]) = y;
  }
}

// ---------------- column sums of kn and vbf -> f32[1024] each ----------------
__global__ __launch_bounds__(256) void k_colsum2(const u16t* __restrict__ kn,
                                                 const u16t* __restrict__ vb,
                                                 float* __restrict__ Kcol,
                                                 float* __restrict__ Vcol) {
  int t = threadIdx.x, c4 = t * 4, r0 = blockIdx.x * 32;
  float sk[4] = {0.f, 0.f, 0.f, 0.f}, sv[4] = {0.f, 0.f, 0.f, 0.f};
  for (int r = r0; r < r0 + 32; r++) {
    u16x4 a = *reinterpret_cast<const u16x4*>(&kn[((size_t)r << 10) + c4]);
    u16x4 b = *reinterpret_cast<const u16x4*>(&vb[((size_t)r << 10) + c4]);
#pragma unroll
    for (int j = 0; j < 4; j++) { sk[j] += bf2f(a[j]); sv[j] += bf2f(b[j]); }
  }
#pragma unroll
  for (int j = 0; j < 4; j++) {
    atomicAdd(&Kcol[c4 + j], sk[j]);
    atomicAdd(&Vcol[c4 + j], sv[j]);
  }
}

// ---------------- k_ktv: per-head M_h = kn_h^T @ v_h  (stored transposed, bf16) ----
__global__ __launch_bounds__(256) void k_ktv(const u16t* __restrict__ knT,
                                             const u16t* __restrict__ vT,
                                             const float* __restrict__ Kcol,
                                             u16t* __restrict__ MT) {
  __shared__ float sls[4][1024];
  int qd = blockIdx.x, h = blockIdx.y;
  int e1t = qd >> 1, e2t = qd & 1;
  int t = threadIdx.x, lane = t & 63, w = t >> 6;
  int l31 = lane & 31, hi = lane >> 5;
  const u16t* ap = knT + (((size_t)((h << 6) + e1t * 32 + l31)) << 11) + w * 512 + hi * 8;
  const u16t* bp = vT  + (((size_t)((h << 6) + e2t * 32 + l31)) << 11) + w * 512 + hi * 8;
  f32x16 acc = {};
#pragma unroll
  for (int k = 0; k < 32; k++) {
    bf16x8 a = *(const bf16x8*)(ap + k * 16);
    bf16x8 b = *(const bf16x8*)(bp + k * 16);
    acc = mf32(a, b, acc);
  }
#pragma unroll
  for (int r = 0; r < 16; r++) {
    int e1l = (r & 3) + 8 * (r >> 2) + 4 * hi;
    sls[w][e1l * 32 + l31] = acc[r];
  }
  __syncthreads();
#pragma unroll
  for (int i = 0; i < 4; i++) {
    int idx = t * 4 + i;
    int e1 = idx >> 5, e2 = idx & 31;
    float s = sls[0][idx] + sls[1][idx] + sls[2][idx] + sls[3][idx];
    MT[h * 4160 + (e2t * 32 + e2) * 64 + e1t * 32 + e1] = f2bf(s);
  }
  if (qd == 0 && t < 64)
    MT[h * 4160 + 4096 + t] = f2bf(Kcol[(h << 6) + t]);
}

// ---------------- k_ctx: ctx = (qn8 @ M + Vcol) / (2048 + qn8.Kcol) -> bf16 ----
__global__ __launch_bounds__(256) void k_ctx(const u16t* __restrict__ qn8,
                                             const u16t* __restrict__ MT,
                                             const float* __restrict__ Vcol,
                                             u16t* __restrict__ ctx) {
  int rt = blockIdx.x;
  int t = threadIdx.x, lane = t & 63, w = t >> 6;
  int l31 = lane & 31, hi = lane >> 5;
  int rowb = rt * 32;
  const u16t* qbase = qn8 + (((size_t)(rowb + l31)) << 10) + hi * 8;
  const f32x16 fz = {};
#pragma unroll
  for (int hh = 0; hh < 4; hh++) {
    int h = w * 4 + hh;
    const u16t* mbase = MT + h * 4160;
    bf16x8 af[4], kf[4];
#pragma unroll
    for (int ks = 0; ks < 4; ks++) {
      af[ks] = *(const bf16x8*)(qbase + (h << 6) + ks * 16);
      kf[ks] = *(const bf16x8*)(mbase + 4096 + ks * 16 + hi * 8);
    }
    f32x16 a0, a1, rd;
#pragma unroll
    for (int ks = 0; ks < 4; ks++) {
      bf16x8 b0 = *(const bf16x8*)(mbase + l31 * 64 + ks * 16 + hi * 8);
      bf16x8 b1 = *(const bf16x8*)(mbase + (32 + l31) * 64 + ks * 16 + hi * 8);
      a0 = mf32(af[ks], b0, ks ? a0 : fz);
      a1 = mf32(af[ks], b1, ks ? a1 : fz);
      rd = mf32(af[ks], kf[ks], ks ? rd : fz);
    }
    float vc0 = Vcol[(h << 6) + l31];
    float vc1 = Vcol[(h << 6) + 32 + l31];
#pragma unroll
    for (int r = 0; r < 16; r++) {
      int row = rowb + (r & 3) + 8 * (r >> 2) + 4 * hi;
      float ri = 1.f / (2048.f + rd[r]);
      u16t* cp = ctx + (((size_t)row) << 10) + (h << 6) + l31;
      cp[0]  = f2bf((a0[r] + vc0) * ri);
      cp[32] = f2bf((a1[r] + vc1) * ri);
    }
  }
}

// ---------------- 128x128x(K=1024) MFMA core, 512 threads (8 waves, 4x2) ----------------
__device__ __forceinline__ void gemm128_acc8(const u16t* __restrict__ A,
                                             const u16t* __restrict__ Bt,
                                             int m0, int n0, f32x4 acc[2][4]) {
  __shared__ __align__(16) u16t As[2][128 * 64];
  __shared__ __align__(16) u16t Bs[2][128 * 64];
  int t = threadIdx.x, lane = t & 63, w = t >> 6;
  int l15 = lane & 15, l16 = lane >> 4;
  int wr = w >> 1, wc = w & 1;
  int srow = t >> 3;                      // 0..63
  int slc = ((t & 7) ^ (srow & 7)) << 3;  // pre-swizzled element offset

#define GSTAGE(KT, NB) do {                                                      \
    _Pragma("unroll")                                                            \
    for (int i = 0; i < 2; i++) {                                                \
      int row_ = srow + i * 64;                                                  \
      int c16_ = (t + i * 512) * 16;                                             \
      gload_lds16(A + ((size_t)(m0 + row_) << 10) + (KT) + slc, (char*)As[NB] + c16_); \
      gload_lds16(Bt + ((size_t)(n0 + row_) << 10) + (KT) + slc, (char*)Bs[NB] + c16_); \
    } } while (0)

  GSTAGE(0, 0);
  for (int ki = 0; ki < 16; ki++) {
    int cur = ki & 1;
    if (ki < 15) {
      GSTAGE((ki + 1) << 6, cur ^ 1);
      asm volatile("s_waitcnt vmcnt(4)" ::: "memory");
    } else {
      asm volatile("s_waitcnt vmcnt(0)" ::: "memory");
    }
    __builtin_amdgcn_s_barrier();
    asm volatile("" ::: "memory");
#pragma unroll
    for (int kk = 0; kk < 2; kk++) {
      bf16x8 af[2], bfr[4];
#pragma unroll
      for (int m = 0; m < 2; m++) {
        int ar = wr * 32 + m * 16 + l15;
        af[m] = *(const bf16x8*)((char*)As[cur] + ar * 128 + ((kk * 64 + l16 * 16) ^ ((ar & 7) << 4)));
      }
#pragma unroll
      for (int n = 0; n < 4; n++) {
        int br = wc * 64 + n * 16 + l15;
        bfr[n] = *(const bf16x8*)((char*)Bs[cur] + br * 128 + ((kk * 64 + l16 * 16) ^ ((br & 7) << 4)));
      }
#pragma unroll
      for (int m = 0; m < 2; m++)
#pragma unroll
        for (int n = 0; n < 4; n++)
          acc[m][n] = __builtin_amdgcn_mfma_f32_16x16x32_bf16(af[m], bfr[n], acc[m][n], 0, 0, 0);
    }
    __builtin_amdgcn_s_barrier();
    asm volatile("" ::: "memory");
  }
#undef GSTAGE
}

// QKV GEMM (bf16 A) with fused bias + ELU + per-head L2-norm epilogue -> bf16
__global__ __launch_bounds__(512) void k_gemm_qkv(const u16t* __restrict__ A,
                                                  const u16t* __restrict__ Wt,
                                                  const float* __restrict__ b0,
                                                  const float* __restrict__ b1,
                                                  const float* __restrict__ b2,
                                                  u16t* __restrict__ out) {
  int bid = blockIdx.y * 8 + blockIdx.x;          // 512 blocks
  int swz = (bid & 7) * 64 + (bid >> 3);          // bijective XCD chunking
  int n0 = (swz & 7) * 128, m0 = (swz >> 3) * 128;
  int seg = (m0 >= 6144) ? 2 : (m0 >= 4096) ? 1 : 0;
  const float* bias = (seg == 0) ? b0 : (seg == 1) ? b1 : b2;
  f32x4 acc[2][4] = {};
  gemm128_acc8(A, Wt + ((size_t)seg << 20), m0, n0, acc);

  int t = threadIdx.x, lane = t & 63, w = t >> 6;
  int l15 = lane & 15, l16 = lane >> 4;
  int wr = w >> 1, wc = w & 1;
  float bb[4];
#pragma unroll
  for (int n = 0; n < 4; n++) bb[n] = bias[n0 + wc * 64 + n * 16 + l15];
  if (seg < 2) {
    float scale0 = (seg == 0) ? 0.125f : 1.f;
#pragma unroll
    for (int m = 0; m < 2; m++) {
#pragma unroll
      for (int r = 0; r < 4; r++) {
        float e[4]; float ss = 0.f;
#pragma unroll
        for (int n = 0; n < 4; n++) {
          float x = acc[m][n][r] + bb[n];
          e[n] = x > 0.f ? x : (__expf(x) - 1.f);
          ss += e[n] * e[n];
        }
        ss += __shfl_xor(ss, 1); ss += __shfl_xor(ss, 2);
        ss += __shfl_xor(ss, 4); ss += __shfl_xor(ss, 8);
        float rinv = rsqrtf(ss) * scale0;
        int row = m0 + wr * 32 + m * 16 + l16 * 4 + r;
#pragma unroll
        for (int n = 0; n < 4; n++)
          out[((size_t)row << 10) + n0 + wc * 64 + n * 16 + l15] = f2bf(e[n] * rinv);
      }
    }
  } else {
#pragma unroll
    for (int m = 0; m < 2; m++) {
      int row = m0 + wr * 32 + m * 16 + l16 * 4;
#pragma unroll
      for (int n = 0; n < 4; n++) {
        int col = n0 + wc * 64 + n * 16 + l15;
#pragma unroll
        for (int r = 0; r < 4; r++)
          out[((size_t)(row + r) << 10) + col] = f2bf(acc[m][n][r] + bb[n]);
      }
    }
  }
}

// O-projection GEMM with fused residual + LN-statistics epilogue -> bf16 H + row sums
__global__ __launch_bounds__(512) void k_gemm_o(const u16t* __restrict__ A,
                                                const u16t* __restrict__ Wt,
                                                const float* __restrict__ bias,
                                                const float* __restrict__ target,
                                                u16t* __restrict__ Hb,
                                                float* __restrict__ rsums) {
  int bid = blockIdx.y * 8 + blockIdx.x;          // 256 blocks
  int swz = (bid & 7) * 32 + (bid >> 3);          // XCD chunking
  int n0 = (swz & 7) * 128, m0 = (swz >> 3) * 128;
  f32x4 acc[2][4] = {};
  gemm128_acc8(A, Wt, m0, n0, acc);
  int t = threadIdx.x, lane = t & 63, w = t >> 6;
  int l15 = lane & 15, l16 = lane >> 4;
  int wr = w >> 1, wc = w & 1;
  float bb[4];
#pragma unroll
  for (int n = 0; n < 4; n++) bb[n] = bias[n0 + wc * 64 + n * 16 + l15];
#pragma unroll
  for (int m = 0; m < 2; m++) {
#pragma unroll
    for (int r = 0; r < 4; r++) {
      int row = m0 + wr * 32 + m * 16 + l16 * 4 + r;
      float s = 0.f, ss = 0.f;
      float xs[4];
#pragma unroll
      for (int n = 0; n < 4; n++) {
        int col = n0 + wc * 64 + n * 16 + l15;
        float x = acc[m][n][r] + bb[n] + target[((size_t)row << 10) + col];
        xs[n] = x; s += x; ss = fmaf(x, x, ss);
      }
#pragma unroll
      for (int n = 0; n < 4; n++)
        Hb[((size_t)row << 10) + n0 + wc * 64 + n * 16 + l15] = f2bf(xs[n]);
      s += __shfl_xor(s, 1); ss += __shfl_xor(ss, 1);
      s += __shfl_xor(s, 2); ss += __shfl_xor(ss, 2);
      s += __shfl_xor(s, 4); ss += __shfl_xor(ss, 4);
      s += __shfl_xor(s, 8); ss += __shfl_xor(ss, 8);
      if (l15 == 0) {
        atomicAdd(&rsums[row * 2], s);
        atomicAdd(&rsums[row * 2 + 1], ss);
      }
    }
  }
}

// ---------------- LayerNorm finalize: pure normalize from precomputed sums ----------------
__global__ __launch_bounds__(256) void k_out_ln(const u16t* __restrict__ Hb,
                                                const float* __restrict__ rsums,
                                                const float* __restrict__ g,
                                                const float* __restrict__ bb,
                                                float* __restrict__ out) {
  int row = blockIdx.x, t = threadIdx.x;
  u16x4 hx = *reinterpret_cast<const u16x4*>(Hb + ((size_t)row << 10) + t * 4);
  float s = rsums[row * 2], ss = rsums[row * 2 + 1];
  float mu = s * (1.f / 1024.f);
  float var = ss * (1.f / 1024.f) - mu * mu;
  float rsn = rsqrtf(var + 1e-12f);
  f32x4 gv = *reinterpret_cast<const f32x4*>(&g[t * 4]);
  f32x4 bv = *reinterpret_cast<const f32x4*>(&bb[t * 4]);
  f32x4 o;
#pragma unroll
  for (int j = 0; j < 4; j++) o[j] = (bf2f(hx[j]) - mu) * rsn * gv[j] + bv[j];
  *reinterpret_cast<f32x4*>(&out[(size_t)row * 1024 + t * 4]) = o;
}

extern "C" void kernel_launch(void* const* d_in, const int* in_sizes, int n_in,
                              void* d_out, int out_size, void* d_ws, size_t ws_size,
                              hipStream_t stream) {
  const float* target = (const float*)d_in[0];
  const float* source = (const float*)d_in[1];
  const float* value  = (const float*)d_in[2];
  const float* Wq = (const float*)d_in[3];
  const float* bq = (const float*)d_in[4];
  const float* Wk = (const float*)d_in[5];
  const float* bk = (const float*)d_in[6];
  const float* Wv = (const float*)d_in[7];
  const float* bvp = (const float*)d_in[8];
  const float* Wo = (const float*)d_in[9];
  const float* bo = (const float*)d_in[10];
  const float* lng = (const float*)d_in[11];
  const float* lnb = (const float*)d_in[12];
  float* out = (float*)d_out;
  char* ws = (char*)d_ws;
  const size_t MB = 1u << 20;

  u16t* abf   = (u16t*)ws;                        // [0,16) target|source|value bf16
  u16t* ctxb  = (u16t*)ws;                        // overlays abf after qkv
  u16t* Wt    = (u16t*)(ws + 16 * MB);
  u16t* Wot   = Wt + ((size_t)3 << 20);
  u16t* qkvnb = (u16t*)(ws + 24 * MB);
  u16t* qnb   = qkvnb;
  u16t* knb   = qkvnb + ((size_t)4096 << 10);
  u16t* vbf   = qkvnb + ((size_t)6144 << 10);
  u16t* knT   = (u16t*)(ws + 40 * MB);
  u16t* vTb   = (u16t*)(ws + 44 * MB);
  u16t* Hb    = (u16t*)(ws + 48 * MB);
  float* Kcolf = (float*)(ws + 64 * MB);
  float* Vcolf = Kcolf + 1024;
  u16t* MTb   = (u16t*)(Vcolf + 1024);
  float* rsums = (float*)(ws + 65 * MB);

  k_cvt3<<<dim3(8192), 256, 0, stream>>>(target, source, value, abf);
  k_wtrans4<<<dim3(16, 16, 4), 256, 0, stream>>>(Wq, Wk, Wv, Wo, Wt, Kcolf, rsums);
  k_gemm_qkv<<<dim3(8, 64), 512, 0, stream>>>(abf, Wt, bq, bk, bvp, qkvnb);
  k_colsum2<<<dim3(64), 256, 0, stream>>>(knb, vbf, Kcolf, Vcolf);
  k_vtrans2<<<dim3(16, 32, 2), 256, 0, stream>>>(knb, vbf, knT, vTb);
  k_ktv<<<dim3(4, 16), 256, 0, stream>>>(knT, vTb, Kcolf, MTb);
  k_ctx<<<dim3(128), 256, 0, stream>>>(qnb, MTb, Vcolf, ctxb);
  k_gemm_o<<<dim3(8, 32), 512, 0, stream>>>(ctxb, Wot, bo, target, Hb, rsums);
  k_out_ln<<<dim3(4096), 256, 0, stream>>>(Hb, rsums, lng, lnb, out);
}

// Round 19
// 87.191 us; speedup vs baseline: 1.9100x; 1.1372x over previous
//
#include <hip/hip_runtime.h>
#include <math.h>

typedef unsigned short u16t;
typedef __attribute__((ext_vector_type(8))) __bf16 bf16x8;
typedef __attribute__((ext_vector_type(4))) float f32x4;
typedef __attribute__((ext_vector_type(16))) float f32x16;
typedef __attribute__((ext_vector_type(4))) unsigned short u16x4;

__device__ __forceinline__ u16t f2bf(float f) {
  union { float f; unsigned u; } v; v.f = f;
  return (u16t)((v.u + 0x7FFFu + ((v.u >> 16) & 1u)) >> 16);
}
__device__ __forceinline__ float bf2f(u16t u) {
  union { unsigned u; float f; } v; v.u = (unsigned)u << 16; return v.f;
}

// async global->LDS, 16B per lane; LDS dest linear (wave-uniform base + lane*16)
__device__ __forceinline__ void gload_lds16(const void* g, void* l) {
  __builtin_amdgcn_global_load_lds(
      (__attribute__((address_space(1))) void*)(uintptr_t)g,
      (__attribute__((address_space(3))) void*)(unsigned)(uintptr_t)l,
      16, 0, 0);
}

__device__ __forceinline__ f32x16 mf32(bf16x8 a, bf16x8 b, f32x16 c) {
  return __builtin_amdgcn_mfma_f32_32x32x16_bf16(a, b, c, 0, 0, 0);
}

// ---------------- fused f32 -> bf16 convert of target|source|value ----------------
__global__ __launch_bounds__(256) void k_cvt3(const float* __restrict__ t0,
                                              const float* __restrict__ s0,
                                              const float* __restrict__ v0,
                                              u16t* __restrict__ out) {
  int row = blockIdx.x, t = threadIdx.x;
  const float* src = row < 4096 ? t0 + ((size_t)row << 10)
                   : row < 6144 ? s0 + ((size_t)(row - 4096) << 10)
                                : v0 + ((size_t)(row - 6144) << 10);
  f32x4 x = *reinterpret_cast<const f32x4*>(src + t * 4);
  u16x4 y;
#pragma unroll
  for (int j = 0; j < 4; j++) y[j] = f2bf(x[j]);
  *reinterpret_cast<u16x4*>(out + ((size_t)row << 10) + t * 4) = y;
}

// ---------------- fused 4x weight transpose + accumulator zeroing ----------------
__global__ __launch_bounds__(256) void k_wtrans4(const float* __restrict__ Wq,
                                                 const float* __restrict__ Wk,
                                                 const float* __restrict__ Wv,
                                                 const float* __restrict__ Wo,
                                                 u16t* __restrict__ dstAll,
                                                 float* __restrict__ KVcol,
                                                 float* __restrict__ rsums) {
  __shared__ u16t tile[64][68];
  int z = blockIdx.z;
  const float* in = z == 0 ? Wq : z == 1 ? Wk : z == 2 ? Wv : Wo;
  u16t* out = dstAll + ((size_t)z << 20);
  int r0 = blockIdx.y * 64, c0 = blockIdx.x * 64;
  int t = threadIdx.x;
  if (z == 0 && blockIdx.y == 0) {
    int g = blockIdx.x * 256 + t;          // 0..4095
    if (g < 2048) KVcol[g] = 0.f;
    rsums[g] = 0.f;
    rsums[g + 4096] = 0.f;
  }
  int rr = t >> 4, q4 = (t & 15) * 4;
#pragma unroll
  for (int i = 0; i < 4; i++) {
    int r = rr + i * 16;
    f32x4 x = *reinterpret_cast<const f32x4*>(&in[(size_t)(r0 + r) * 1024 + c0 + q4]);
#pragma unroll
    for (int j = 0; j < 4; j++) tile[r][q4 + j] = f2bf(x[j]);
  }
  __syncthreads();
#pragma unroll
  for (int i = 0; i < 4; i++) {
    int c = rr + i * 16;
    u16x4 y;
#pragma unroll
    for (int j = 0; j < 4; j++) y[j] = tile[q4 + j][c];
    *reinterpret_cast<u16x4*>(&out[(size_t)(c0 + c) * 1024 + r0 + q4]) = y;
  }
}

// ---------------- k_ktv: per-head M_h = kn_h^T @ v_h  (stored transposed, bf16) ----
__global__ __launch_bounds__(256) void k_ktv(const u16t* __restrict__ knT,
                                             const u16t* __restrict__ vT,
                                             const float* __restrict__ Kcol,
                                             u16t* __restrict__ MT) {
  __shared__ float sls[4][1024];
  int qd = blockIdx.x, h = blockIdx.y;
  int e1t = qd >> 1, e2t = qd & 1;
  int t = threadIdx.x, lane = t & 63, w = t >> 6;
  int l31 = lane & 31, hi = lane >> 5;
  const u16t* ap = knT + (((size_t)((h << 6) + e1t * 32 + l31)) << 11) + w * 512 + hi * 8;
  const u16t* bp = vT  + (((size_t)((h << 6) + e2t * 32 + l31)) << 11) + w * 512 + hi * 8;
  f32x16 acc = {};
#pragma unroll
  for (int k = 0; k < 32; k++) {
    bf16x8 a = *(const bf16x8*)(ap + k * 16);
    bf16x8 b = *(const bf16x8*)(bp + k * 16);
    acc = mf32(a, b, acc);
  }
#pragma unroll
  for (int r = 0; r < 16; r++) {
    int e1l = (r & 3) + 8 * (r >> 2) + 4 * hi;
    sls[w][e1l * 32 + l31] = acc[r];
  }
  __syncthreads();
#pragma unroll
  for (int i = 0; i < 4; i++) {
    int idx = t * 4 + i;
    int e1 = idx >> 5, e2 = idx & 31;
    float s = sls[0][idx] + sls[1][idx] + sls[2][idx] + sls[3][idx];
    MT[h * 4160 + (e2t * 32 + e2) * 64 + e1t * 32 + e1] = f2bf(s);
  }
  if (qd == 0 && t < 64)
    MT[h * 4160 + 4096 + t] = f2bf(Kcol[(h << 6) + t]);
}

// ---------------- k_ctx: ctx = (qn8 @ M + Vcol) / (2048 + qn8.Kcol) -> bf16 ----
__global__ __launch_bounds__(256) void k_ctx(const u16t* __restrict__ qn8,
                                             const u16t* __restrict__ MT,
                                             const float* __restrict__ Vcol,
                                             u16t* __restrict__ ctx) {
  int rt = blockIdx.x;
  int t = threadIdx.x, lane = t & 63, w = t >> 6;
  int l31 = lane & 31, hi = lane >> 5;
  int rowb = rt * 32;
  const u16t* qbase = qn8 + (((size_t)(rowb + l31)) << 10) + hi * 8;
  const f32x16 fz = {};
#pragma unroll
  for (int hh = 0; hh < 4; hh++) {
    int h = w * 4 + hh;
    const u16t* mbase = MT + h * 4160;
    bf16x8 af[4], kf[4];
#pragma unroll
    for (int ks = 0; ks < 4; ks++) {
      af[ks] = *(const bf16x8*)(qbase + (h << 6) + ks * 16);
      kf[ks] = *(const bf16x8*)(mbase + 4096 + ks * 16 + hi * 8);
    }
    f32x16 a0, a1, rd;
#pragma unroll
    for (int ks = 0; ks < 4; ks++) {
      bf16x8 b0 = *(const bf16x8*)(mbase + l31 * 64 + ks * 16 + hi * 8);
      bf16x8 b1 = *(const bf16x8*)(mbase + (32 + l31) * 64 + ks * 16 + hi * 8);
      a0 = mf32(af[ks], b0, ks ? a0 : fz);
      a1 = mf32(af[ks], b1, ks ? a1 : fz);
      rd = mf32(af[ks], kf[ks], ks ? rd : fz);
    }
    float vc0 = Vcol[(h << 6) + l31];
    float vc1 = Vcol[(h << 6) + 32 + l31];
#pragma unroll
    for (int r = 0; r < 16; r++) {
      int row = rowb + (r & 3) + 8 * (r >> 2) + 4 * hi;
      float ri = 1.f / (2048.f + rd[r]);
      u16t* cp = ctx + (((size_t)row) << 10) + (h << 6) + l31;
      cp[0]  = f2bf((a0[r] + vc0) * ri);
      cp[32] = f2bf((a1[r] + vc1) * ri);
    }
  }
}

// ---------------- 128x128x(K=1024) MFMA core, 512 threads (8 waves, 4x2) ----------------
__device__ __forceinline__ void gemm128_acc8(const u16t* __restrict__ A,
                                             const u16t* __restrict__ Bt,
                                             int m0, int n0, f32x4 acc[2][4]) {
  __shared__ __align__(16) u16t As[2][128 * 64];
  __shared__ __align__(16) u16t Bs[2][128 * 64];
  int t = threadIdx.x, lane = t & 63, w = t >> 6;
  int l15 = lane & 15, l16 = lane >> 4;
  int wr = w >> 1, wc = w & 1;
  int srow = t >> 3;                      // 0..63
  int slc = ((t & 7) ^ (srow & 7)) << 3;  // pre-swizzled element offset

#define GSTAGE(KT, NB) do {                                                      \
    _Pragma("unroll")                                                            \
    for (int i = 0; i < 2; i++) {                                                \
      int row_ = srow + i * 64;                                                  \
      int c16_ = (t + i * 512) * 16;                                             \
      gload_lds16(A + ((size_t)(m0 + row_) << 10) + (KT) + slc, (char*)As[NB] + c16_); \
      gload_lds16(Bt + ((size_t)(n0 + row_) << 10) + (KT) + slc, (char*)Bs[NB] + c16_); \
    } } while (0)

  GSTAGE(0, 0);
  for (int ki = 0; ki < 16; ki++) {
    int cur = ki & 1;
    if (ki < 15) {
      GSTAGE((ki + 1) << 6, cur ^ 1);
      asm volatile("s_waitcnt vmcnt(4)" ::: "memory");
    } else {
      asm volatile("s_waitcnt vmcnt(0)" ::: "memory");
    }
    __builtin_amdgcn_s_barrier();
    asm volatile("" ::: "memory");
#pragma unroll
    for (int kk = 0; kk < 2; kk++) {
      bf16x8 af[2], bfr[4];
#pragma unroll
      for (int m = 0; m < 2; m++) {
        int ar = wr * 32 + m * 16 + l15;
        af[m] = *(const bf16x8*)((char*)As[cur] + ar * 128 + ((kk * 64 + l16 * 16) ^ ((ar & 7) << 4)));
      }
#pragma unroll
      for (int n = 0; n < 4; n++) {
        int br = wc * 64 + n * 16 + l15;
        bfr[n] = *(const bf16x8*)((char*)Bs[cur] + br * 128 + ((kk * 64 + l16 * 16) ^ ((br & 7) << 4)));
      }
#pragma unroll
      for (int m = 0; m < 2; m++)
#pragma unroll
        for (int n = 0; n < 4; n++)
          acc[m][n] = __builtin_amdgcn_mfma_f32_16x16x32_bf16(af[m], bfr[n], acc[m][n], 0, 0, 0);
    }
    __builtin_amdgcn_s_barrier();
    asm volatile("" ::: "memory");
  }
#undef GSTAGE
}

// QKV GEMM (bf16 A), fused epilogues:
//  seg 0 (Q): bias+ELU+L2norm*0.125 -> qn8 row-major
//  seg 1 (K): bias+ELU+L2norm -> knT [1024][2048] transposed + Kcol atomics
//  seg 2 (V): bias -> vT [1024][2048] transposed + Vcol atomics
__global__ __launch_bounds__(512) void k_gemm_qkv(const u16t* __restrict__ A,
                                                  const u16t* __restrict__ Wt,
                                                  const float* __restrict__ b0,
                                                  const float* __restrict__ b1,
                                                  const float* __restrict__ b2,
                                                  u16t* __restrict__ qn8,
                                                  u16t* __restrict__ knT,
                                                  u16t* __restrict__ vT,
                                                  float* __restrict__ Kcol,
                                                  float* __restrict__ Vcol) {
  int bid = blockIdx.y * 8 + blockIdx.x;          // 512 blocks
  int swz = (bid & 7) * 64 + (bid >> 3);          // bijective XCD chunking
  int n0 = (swz & 7) * 128, m0 = (swz >> 3) * 128;
  int seg = (m0 >= 6144) ? 2 : (m0 >= 4096) ? 1 : 0;
  const float* bias = (seg == 0) ? b0 : (seg == 1) ? b1 : b2;
  f32x4 acc[2][4] = {};
  gemm128_acc8(A, Wt + ((size_t)seg << 20), m0, n0, acc);

  int t = threadIdx.x, lane = t & 63, w = t >> 6;
  int l15 = lane & 15, l16 = lane >> 4;
  int wr = w >> 1, wc = w & 1;
  float bb[4];
#pragma unroll
  for (int n = 0; n < 4; n++) bb[n] = bias[n0 + wc * 64 + n * 16 + l15];

  if (seg == 0) {
#pragma unroll
    for (int m = 0; m < 2; m++) {
#pragma unroll
      for (int r = 0; r < 4; r++) {
        float e[4]; float ss = 0.f;
#pragma unroll
        for (int n = 0; n < 4; n++) {
          float x = acc[m][n][r] + bb[n];
          e[n] = x > 0.f ? x : (__expf(x) - 1.f);
          ss += e[n] * e[n];
        }
        ss += __shfl_xor(ss, 1); ss += __shfl_xor(ss, 2);
        ss += __shfl_xor(ss, 4); ss += __shfl_xor(ss, 8);
        float rinv = rsqrtf(ss) * 0.125f;
        int row = m0 + wr * 32 + m * 16 + l16 * 4 + r;
#pragma unroll
        for (int n = 0; n < 4; n++)
          qn8[((size_t)row << 10) + n0 + wc * 64 + n * 16 + l15] = f2bf(e[n] * rinv);
      }
    }
  } else {
    u16t* outT = (seg == 1) ? knT : vT;
    float* colp = (seg == 1) ? Kcol : Vcol;
    int mloc = m0 - ((seg == 1) ? 4096 : 6144);
    float cs[4] = {0.f, 0.f, 0.f, 0.f};
#pragma unroll
    for (int m = 0; m < 2; m++) {
      u16x4 tv[4];
#pragma unroll
      for (int r = 0; r < 4; r++) {
        float v[4];
        if (seg == 1) {
          float e[4]; float ss = 0.f;
#pragma unroll
          for (int n = 0; n < 4; n++) {
            float x = acc[m][n][r] + bb[n];
            e[n] = x > 0.f ? x : (__expf(x) - 1.f);
            ss += e[n] * e[n];
          }
          ss += __shfl_xor(ss, 1); ss += __shfl_xor(ss, 2);
          ss += __shfl_xor(ss, 4); ss += __shfl_xor(ss, 8);
          float rinv = rsqrtf(ss);
#pragma unroll
          for (int n = 0; n < 4; n++) v[n] = e[n] * rinv;
        } else {
#pragma unroll
          for (int n = 0; n < 4; n++) v[n] = acc[m][n][r] + bb[n];
        }
#pragma unroll
        for (int n = 0; n < 4; n++) { tv[n][r] = f2bf(v[n]); cs[n] += v[n]; }
      }
      int rowb = mloc + wr * 32 + m * 16 + l16 * 4;
#pragma unroll
      for (int n = 0; n < 4; n++) {
        int col = n0 + wc * 64 + n * 16 + l15;
        *reinterpret_cast<u16x4*>(outT + ((size_t)col << 11) + rowb) = tv[n];
      }
    }
#pragma unroll
    for (int n = 0; n < 4; n++) {
      float s = cs[n];
      s += __shfl_xor(s, 16); s += __shfl_xor(s, 32);
      if (l16 == 0) atomicAdd(&colp[n0 + wc * 64 + n * 16 + l15], s);
    }
  }
}

// O-projection GEMM with fused residual + LN-statistics epilogue -> bf16 H + row sums
__global__ __launch_bounds__(512) void k_gemm_o(const u16t* __restrict__ A,
                                                const u16t* __restrict__ Wt,
                                                const float* __restrict__ bias,
                                                const float* __restrict__ target,
                                                u16t* __restrict__ Hb,
                                                float* __restrict__ rsums) {
  int bid = blockIdx.y * 8 + blockIdx.x;          // 256 blocks
  int swz = (bid & 7) * 32 + (bid >> 3);          // XCD chunking
  int n0 = (swz & 7) * 128, m0 = (swz >> 3) * 128;
  f32x4 acc[2][4] = {};
  gemm128_acc8(A, Wt, m0, n0, acc);
  int t = threadIdx.x, lane = t & 63, w = t >> 6;
  int l15 = lane & 15, l16 = lane >> 4;
  int wr = w >> 1, wc = w & 1;
  float bb[4];
#pragma unroll
  for (int n = 0; n < 4; n++) bb[n] = bias[n0 + wc * 64 + n * 16 + l15];
#pragma unroll
  for (int m = 0; m < 2; m++) {
#pragma unroll
    for (int r = 0; r < 4; r++) {
      int row = m0 + wr * 32 + m * 16 + l16 * 4 + r;
      float s = 0.f, ss = 0.f;
      float xs[4];
#pragma unroll
      for (int n = 0; n < 4; n++) {
        int col = n0 + wc * 64 + n * 16 + l15;
        float x = acc[m][n][r] + bb[n] + target[((size_t)row << 10) + col];
        xs[n] = x; s += x; ss = fmaf(x, x, ss);
      }
#pragma unroll
      for (int n = 0; n < 4; n++)
        Hb[((size_t)row << 10) + n0 + wc * 64 + n * 16 + l15] = f2bf(xs[n]);
      s += __shfl_xor(s, 1); ss += __shfl_xor(ss, 1);
      s += __shfl_xor(s, 2); ss += __shfl_xor(ss, 2);
      s += __shfl_xor(s, 4); ss += __shfl_xor(ss, 4);
      s += __shfl_xor(s, 8); ss += __shfl_xor(ss, 8);
      if (l15 == 0) {
        atomicAdd(&rsums[row * 2], s);
        atomicAdd(&rsums[row * 2 + 1], ss);
      }
    }
  }
}

// ---------------- LayerNorm finalize: pure normalize from precomputed sums ----------------
__global__ __launch_bounds__(256) void k_out_ln(const u16t* __restrict__ Hb,
                                                const float* __restrict__ rsums,
                                                const float* __restrict__ g,
                                                const float* __restrict__ bb,
                                                float* __restrict__ out) {
  int row = blockIdx.x, t = threadIdx.x;
  u16x4 hx = *reinterpret_cast<const u16x4*>(Hb + ((size_t)row << 10) + t * 4);
  float s = rsums[row * 2], ss = rsums[row * 2 + 1];
  float mu = s * (1.f / 1024.f);
  float var = ss * (1.f / 1024.f) - mu * mu;
  float rsn = rsqrtf(var + 1e-12f);
  f32x4 gv = *reinterpret_cast<const f32x4*>(&g[t * 4]);
  f32x4 bv = *reinterpret_cast<const f32x4*>(&bb[t * 4]);
  f32x4 o;
#pragma unroll
  for (int j = 0; j < 4; j++) o[j] = (bf2f(hx[j]) - mu) * rsn * gv[j] + bv[j];
  *reinterpret_cast<f32x4*>(&out[(size_t)row * 1024 + t * 4]) = o;
}

extern "C" void kernel_launch(void* const* d_in, const int* in_sizes, int n_in,
                              void* d_out, int out_size, void* d_ws, size_t ws_size,
                              hipStream_t stream) {
  const float* target = (const float*)d_in[0];
  const float* source = (const float*)d_in[1];
  const float* value  = (const float*)d_in[2];
  const float* Wq = (const float*)d_in[3];
  const float* bq = (const float*)d_in[4];
  const float* Wk = (const float*)d_in[5];
  const float* bk = (const float*)d_in[6];
  const float* Wv = (const float*)d_in[7];
  const float* bvp = (const float*)d_in[8];
  const float* Wo = (const float*)d_in[9];
  const float* bo = (const float*)d_in[10];
  const float* lng = (const float*)d_in[11];
  const float* lnb = (const float*)d_in[12];
  float* out = (float*)d_out;
  char* ws = (char*)d_ws;
  const size_t MB = 1u << 20;

  // ws layout:
  //  [0,16)  abf bf16 [8192][1024] target|source|value (ctxb overlays [0,8) after qkv)
  //  [16,24) Wt bf16 4x transposed weights
  //  [24,32) qn8 bf16 [4096][1024]
  //  [40,44) knT bf16 [1024][2048]
  //  [44,48) vT  bf16 [1024][2048]
  //  [48,56) Hb bf16 [4096][1024]
  //  [64MB)  Kcol | Vcol | MT    [65MB) rsums
  u16t* abf   = (u16t*)ws;
  u16t* ctxb  = (u16t*)ws;
  u16t* Wt    = (u16t*)(ws + 16 * MB);
  u16t* Wot   = Wt + ((size_t)3 << 20);
  u16t* qnb   = (u16t*)(ws + 24 * MB);
  u16t* knT   = (u16t*)(ws + 40 * MB);
  u16t* vTb   = (u16t*)(ws + 44 * MB);
  u16t* Hb    = (u16t*)(ws + 48 * MB);
  float* Kcolf = (float*)(ws + 64 * MB);
  float* Vcolf = Kcolf + 1024;
  u16t* MTb   = (u16t*)(Vcolf + 1024);
  float* rsums = (float*)(ws + 65 * MB);

  k_cvt3<<<dim3(8192), 256, 0, stream>>>(target, source, value, abf);
  k_wtrans4<<<dim3(16, 16, 4), 256, 0, stream>>>(Wq, Wk, Wv, Wo, Wt, Kcolf, rsums);
  k_gemm_qkv<<<dim3(8, 64), 512, 0, stream>>>(abf, Wt, bq, bk, bvp, qnb, knT, vTb, Kcolf, Vcolf);
  k_ktv<<<dim3(4, 16), 256, 0, stream>>>(knT, vTb, Kcolf, MTb);
  k_ctx<<<dim3(128), 256, 0, stream>>>(qnb, MTb, Vcolf, ctxb);
  k_gemm_o<<<dim3(8, 32), 512, 0, stream>>>(ctxb, Wot, bo, target, Hb, rsums);
  k_out_ln<<<dim3(4096), 256, 0, stream>>>(Hb, rsums, lng, lnb, out);
}

// Round 20
// 85.499 us; speedup vs baseline: 1.9478x; 1.0198x over previous
//
#include <hip/hip_runtime.h>
#include <math.h>

typedef unsigned short u16t;
typedef __attribute__((ext_vector_type(8))) __bf16 bf16x8;
typedef __attribute__((ext_vector_type(4))) float f32x4;
typedef __attribute__((ext_vector_type(16))) float f32x16;
typedef __attribute__((ext_vector_type(4))) unsigned short u16x4;

__device__ __forceinline__ u16t f2bf(float f) {
  union { float f; unsigned u; } v; v.f = f;
  return (u16t)((v.u + 0x7FFFu + ((v.u >> 16) & 1u)) >> 16);
}
__device__ __forceinline__ float bf2f(u16t u) {
  union { unsigned u; float f; } v; v.u = (unsigned)u << 16; return v.f;
}

// async global->LDS, 16B per lane; LDS dest linear (wave-uniform base + lane*16)
__device__ __forceinline__ void gload_lds16(const void* g, void* l) {
  __builtin_amdgcn_global_load_lds(
      (__attribute__((address_space(1))) void*)(uintptr_t)g,
      (__attribute__((address_space(3))) void*)(unsigned)(uintptr_t)l,
      16, 0, 0);
}

__device__ __forceinline__ f32x16 mf32(bf16x8 a, bf16x8 b, f32x16 c) {
  return __builtin_amdgcn_mfma_f32_32x32x16_bf16(a, b, c, 0, 0, 0);
}

// pack 8 f32 (2x f32x4) -> bf16x8 via v_cvt_pk_bf16_f32 (RNE)
__device__ __forceinline__ bf16x8 pk8(f32x4 a, f32x4 b) {
  union { unsigned u[4]; bf16x8 v; } r;
  asm("v_cvt_pk_bf16_f32 %0, %1, %2" : "=v"(r.u[0]) : "v"(a[0]), "v"(a[1]));
  asm("v_cvt_pk_bf16_f32 %0, %1, %2" : "=v"(r.u[1]) : "v"(a[2]), "v"(a[3]));
  asm("v_cvt_pk_bf16_f32 %0, %1, %2" : "=v"(r.u[2]) : "v"(b[0]), "v"(b[1]));
  asm("v_cvt_pk_bf16_f32 %0, %1, %2" : "=v"(r.u[3]) : "v"(b[2]), "v"(b[3]));
  return r.v;
}

// ---------------- fused 4x weight transpose + accumulator zeroing ----------------
__global__ __launch_bounds__(256) void k_wtrans4(const float* __restrict__ Wq,
                                                 const float* __restrict__ Wk,
                                                 const float* __restrict__ Wv,
                                                 const float* __restrict__ Wo,
                                                 u16t* __restrict__ dstAll,
                                                 float* __restrict__ KVcol,
                                                 float* __restrict__ rsums) {
  __shared__ u16t tile[64][68];
  int z = blockIdx.z;
  const float* in = z == 0 ? Wq : z == 1 ? Wk : z == 2 ? Wv : Wo;
  u16t* out = dstAll + ((size_t)z << 20);
  int r0 = blockIdx.y * 64, c0 = blockIdx.x * 64;
  int t = threadIdx.x;
  if (z == 0 && blockIdx.y == 0) {
    int g = blockIdx.x * 256 + t;          // 0..4095
    if (g < 2048) KVcol[g] = 0.f;
    rsums[g] = 0.f;
    rsums[g + 4096] = 0.f;
  }
  int rr = t >> 4, q4 = (t & 15) * 4;
#pragma unroll
  for (int i = 0; i < 4; i++) {
    int r = rr + i * 16;
    f32x4 x = *reinterpret_cast<const f32x4*>(&in[(size_t)(r0 + r) * 1024 + c0 + q4]);
#pragma unroll
    for (int j = 0; j < 4; j++) tile[r][q4 + j] = f2bf(x[j]);
  }
  __syncthreads();
#pragma unroll
  for (int i = 0; i < 4; i++) {
    int c = rr + i * 16;
    u16x4 y;
#pragma unroll
    for (int j = 0; j < 4; j++) y[j] = tile[q4 + j][c];
    *reinterpret_cast<u16x4*>(&out[(size_t)(c0 + c) * 1024 + r0 + q4]) = y;
  }
}

// ---------------- k_ktv: per-head M_h = kn_h^T @ v_h  (stored transposed, bf16) ----
__global__ __launch_bounds__(256) void k_ktv(const u16t* __restrict__ knT,
                                             const u16t* __restrict__ vT,
                                             const float* __restrict__ Kcol,
                                             u16t* __restrict__ MT) {
  __shared__ float sls[4][1024];
  int qd = blockIdx.x, h = blockIdx.y;
  int e1t = qd >> 1, e2t = qd & 1;
  int t = threadIdx.x, lane = t & 63, w = t >> 6;
  int l31 = lane & 31, hi = lane >> 5;
  const u16t* ap = knT + (((size_t)((h << 6) + e1t * 32 + l31)) << 11) + w * 512 + hi * 8;
  const u16t* bp = vT  + (((size_t)((h << 6) + e2t * 32 + l31)) << 11) + w * 512 + hi * 8;
  f32x16 acc = {};
#pragma unroll
  for (int k = 0; k < 32; k++) {
    bf16x8 a = *(const bf16x8*)(ap + k * 16);
    bf16x8 b = *(const bf16x8*)(bp + k * 16);
    acc = mf32(a, b, acc);
  }
#pragma unroll
  for (int r = 0; r < 16; r++) {
    int e1l = (r & 3) + 8 * (r >> 2) + 4 * hi;
    sls[w][e1l * 32 + l31] = acc[r];
  }
  __syncthreads();
#pragma unroll
  for (int i = 0; i < 4; i++) {
    int idx = t * 4 + i;
    int e1 = idx >> 5, e2 = idx & 31;
    float s = sls[0][idx] + sls[1][idx] + sls[2][idx] + sls[3][idx];
    MT[h * 4160 + (e2t * 32 + e2) * 64 + e1t * 32 + e1] = f2bf(s);
  }
  if (qd == 0 && t < 64)
    MT[h * 4160 + 4096 + t] = f2bf(Kcol[(h << 6) + t]);
}

// ---------------- k_ctx: ctx = (qn8 @ M + Vcol) / (2048 + qn8.Kcol) -> bf16 ----
__global__ __launch_bounds__(256) void k_ctx(const u16t* __restrict__ qn8,
                                             const u16t* __restrict__ MT,
                                             const float* __restrict__ Vcol,
                                             u16t* __restrict__ ctx) {
  int rt = blockIdx.x;
  int t = threadIdx.x, lane = t & 63, w = t >> 6;
  int l31 = lane & 31, hi = lane >> 5;
  int rowb = rt * 32;
  const u16t* qbase = qn8 + (((size_t)(rowb + l31)) << 10) + hi * 8;
  const f32x16 fz = {};
#pragma unroll
  for (int hh = 0; hh < 4; hh++) {
    int h = w * 4 + hh;
    const u16t* mbase = MT + h * 4160;
    bf16x8 af[4], kf[4];
#pragma unroll
    for (int ks = 0; ks < 4; ks++) {
      af[ks] = *(const bf16x8*)(qbase + (h << 6) + ks * 16);
      kf[ks] = *(const bf16x8*)(mbase + 4096 + ks * 16 + hi * 8);
    }
    f32x16 a0, a1, rd;
#pragma unroll
    for (int ks = 0; ks < 4; ks++) {
      bf16x8 b0 = *(const bf16x8*)(mbase + l31 * 64 + ks * 16 + hi * 8);
      bf16x8 b1 = *(const bf16x8*)(mbase + (32 + l31) * 64 + ks * 16 + hi * 8);
      a0 = mf32(af[ks], b0, ks ? a0 : fz);
      a1 = mf32(af[ks], b1, ks ? a1 : fz);
      rd = mf32(af[ks], kf[ks], ks ? rd : fz);
    }
    float vc0 = Vcol[(h << 6) + l31];
    float vc1 = Vcol[(h << 6) + 32 + l31];
#pragma unroll
    for (int r = 0; r < 16; r++) {
      int row = rowb + (r & 3) + 8 * (r >> 2) + 4 * hi;
      float ri = 1.f / (2048.f + rd[r]);
      u16t* cp = ctx + (((size_t)row) << 10) + (h << 6) + l31;
      cp[0]  = f2bf((a0[r] + vc0) * ri);
      cp[32] = f2bf((a1[r] + vc1) * ri);
    }
  }
}

// ---------------- QKV GEMM v4: f32 A via DMA'd LDS (BK=32), B bf16 DMA ----------------
// 128x128 tile, 512 threads (8 waves 4x2, wave 32x64, acc[2][4]).
// A f32 [128][32] 16KB/buf (XOR row&7 swz), B bf16 [128][32] 8KB/buf (XOR row&3 swz).
// 2 buffers each (48KB), counted vmcnt(3), 2 barriers/iter, 32 K-iters.
__global__ __launch_bounds__(512) void k_gemm_qkv(const float* __restrict__ target,
                                                  const float* __restrict__ source,
                                                  const float* __restrict__ value,
                                                  const u16t* __restrict__ Wt,
                                                  const float* __restrict__ b0,
                                                  const float* __restrict__ b1,
                                                  const float* __restrict__ b2,
                                                  u16t* __restrict__ qn8,
                                                  u16t* __restrict__ knT,
                                                  u16t* __restrict__ vT,
                                                  float* __restrict__ Kcol,
                                                  float* __restrict__ Vcol) {
  __shared__ __align__(16) char AsB[2][16384];
  __shared__ __align__(16) char BsB[2][8192];
  int bid = blockIdx.y * 8 + blockIdx.x;          // 512 blocks
  int swz = (bid & 7) * 64 + (bid >> 3);          // bijective XCD chunking
  int n0 = (swz & 7) * 128, m0 = (swz >> 3) * 128;
  int seg = (m0 >= 6144) ? 2 : (m0 >= 4096) ? 1 : 0;
  const float* bias = (seg == 0) ? b0 : (seg == 1) ? b1 : b2;
  const float* Af = (seg == 0) ? target : (seg == 1) ? source : value;
  int mloc = m0 - ((seg == 0) ? 0 : (seg == 1) ? 4096 : 6144);
  const u16t* Bseg = Wt + ((size_t)seg << 20);

  int t = threadIdx.x, lane = t & 63, w = t >> 6;
  int l15 = lane & 15, l16 = lane >> 4;
  int wr = w >> 1, wc = w & 1;
  f32x4 acc[2][4] = {};

  // A stage: chunks ic = t, t+512; row = ic>>3, c = ic&7; pre-swizzled source
  int ar0 = t >> 3, ac0 = t & 7;
  int ae0 = ((ac0 ^ (ar0 & 7)) << 2);             // element offset (f32)
  // B stage: chunk t; row = t>>2, c = t&3
  int br0 = t >> 2, bc0 = t & 3;
  int be0 = ((bc0 ^ (br0 & 3)) << 3);             // element offset (bf16)

#define QSTG(KT, NB) do {                                                        \
    gload_lds16(Af + (((size_t)(mloc + ar0)) << 10) + (KT) + ae0,                \
                AsB[NB] + t * 16);                                               \
    gload_lds16(Af + (((size_t)(mloc + 64 + ar0)) << 10) + (KT) + ae0,           \
                AsB[NB] + 8192 + t * 16);                                        \
    gload_lds16(Bseg + (((size_t)(n0 + br0)) << 10) + (KT) + be0,                \
                BsB[NB] + t * 16);                                               \
  } while (0)

  QSTG(0, 0);
  for (int ki = 0; ki < 32; ki++) {
    int cur = ki & 1;
    if (ki < 31) {
      QSTG((ki + 1) << 5, cur ^ 1);
      asm volatile("s_waitcnt vmcnt(3)" ::: "memory");
    } else {
      asm volatile("s_waitcnt vmcnt(0)" ::: "memory");
    }
    __builtin_amdgcn_s_barrier();
    asm volatile("" ::: "memory");
    const char* ab = AsB[cur];
    const char* bb = BsB[cur];
    bf16x8 af[2], bfr[4];
#pragma unroll
    for (int m = 0; m < 2; m++) {
      int ar = wr * 32 + m * 16 + l15;
      int sw = (ar & 7) << 4;
      int base = ar * 128 + l16 * 32;
      f32x4 c0 = *(const f32x4*)(ab + (base ^ sw));
      f32x4 c1 = *(const f32x4*)(ab + ((base + 16) ^ sw));
      af[m] = pk8(c0, c1);
    }
#pragma unroll
    for (int n = 0; n < 4; n++) {
      int br = wc * 64 + n * 16 + l15;
      bfr[n] = *(const bf16x8*)(bb + br * 64 + ((l16 * 16) ^ ((br & 3) << 4)));
    }
#pragma unroll
    for (int m = 0; m < 2; m++)
#pragma unroll
      for (int n = 0; n < 4; n++)
        acc[m][n] = __builtin_amdgcn_mfma_f32_16x16x32_bf16(af[m], bfr[n], acc[m][n], 0, 0, 0);
    __builtin_amdgcn_s_barrier();
    asm volatile("" ::: "memory");
  }
#undef QSTG

  float bb4[4];
#pragma unroll
  for (int n = 0; n < 4; n++) bb4[n] = bias[n0 + wc * 64 + n * 16 + l15];

  if (seg == 0) {
#pragma unroll
    for (int m = 0; m < 2; m++) {
#pragma unroll
      for (int r = 0; r < 4; r++) {
        float e[4]; float ss = 0.f;
#pragma unroll
        for (int n = 0; n < 4; n++) {
          float x = acc[m][n][r] + bb4[n];
          e[n] = x > 0.f ? x : (__expf(x) - 1.f);
          ss += e[n] * e[n];
        }
        ss += __shfl_xor(ss, 1); ss += __shfl_xor(ss, 2);
        ss += __shfl_xor(ss, 4); ss += __shfl_xor(ss, 8);
        float rinv = rsqrtf(ss) * 0.125f;
        int row = m0 + wr * 32 + m * 16 + l16 * 4 + r;
#pragma unroll
        for (int n = 0; n < 4; n++)
          qn8[((size_t)row << 10) + n0 + wc * 64 + n * 16 + l15] = f2bf(e[n] * rinv);
      }
    }
  } else {
    u16t* outT = (seg == 1) ? knT : vT;
    float* colp = (seg == 1) ? Kcol : Vcol;
    float cs[4] = {0.f, 0.f, 0.f, 0.f};
#pragma unroll
    for (int m = 0; m < 2; m++) {
      u16x4 tv[4];
#pragma unroll
      for (int r = 0; r < 4; r++) {
        float v[4];
        if (seg == 1) {
          float e[4]; float ss = 0.f;
#pragma unroll
          for (int n = 0; n < 4; n++) {
            float x = acc[m][n][r] + bb4[n];
            e[n] = x > 0.f ? x : (__expf(x) - 1.f);
            ss += e[n] * e[n];
          }
          ss += __shfl_xor(ss, 1); ss += __shfl_xor(ss, 2);
          ss += __shfl_xor(ss, 4); ss += __shfl_xor(ss, 8);
          float rinv = rsqrtf(ss);
#pragma unroll
          for (int n = 0; n < 4; n++) v[n] = e[n] * rinv;
        } else {
#pragma unroll
          for (int n = 0; n < 4; n++) v[n] = acc[m][n][r] + bb4[n];
        }
#pragma unroll
        for (int n = 0; n < 4; n++) { tv[n][r] = f2bf(v[n]); cs[n] += v[n]; }
      }
      int rowb = mloc + wr * 32 + m * 16 + l16 * 4;
#pragma unroll
      for (int n = 0; n < 4; n++) {
        int col = n0 + wc * 64 + n * 16 + l15;
        *reinterpret_cast<u16x4*>(outT + ((size_t)col << 11) + rowb) = tv[n];
      }
    }
#pragma unroll
    for (int n = 0; n < 4; n++) {
      float s = cs[n];
      s += __shfl_xor(s, 16); s += __shfl_xor(s, 32);
      if (l16 == 0) atomicAdd(&colp[n0 + wc * 64 + n * 16 + l15], s);
    }
  }
}

// ---------------- 128x128x(K=1024) MFMA core, 512 threads (R17-proven, bf16 A) ----------
__device__ __forceinline__ void gemm128_acc8(const u16t* __restrict__ A,
                                             const u16t* __restrict__ Bt,
                                             int m0, int n0, f32x4 acc[2][4]) {
  __shared__ __align__(16) u16t As[2][128 * 64];
  __shared__ __align__(16) u16t Bs[2][128 * 64];
  int t = threadIdx.x, lane = t & 63, w = t >> 6;
  int l15 = lane & 15, l16 = lane >> 4;
  int wr = w >> 1, wc = w & 1;
  int srow = t >> 3;                      // 0..63
  int slc = ((t & 7) ^ (srow & 7)) << 3;  // pre-swizzled element offset

#define GSTAGE(KT, NB) do {                                                      \
    _Pragma("unroll")                                                            \
    for (int i = 0; i < 2; i++) {                                                \
      int row_ = srow + i * 64;                                                  \
      int c16_ = (t + i * 512) * 16;                                             \
      gload_lds16(A + ((size_t)(m0 + row_) << 10) + (KT) + slc, (char*)As[NB] + c16_); \
      gload_lds16(Bt + ((size_t)(n0 + row_) << 10) + (KT) + slc, (char*)Bs[NB] + c16_); \
    } } while (0)

  GSTAGE(0, 0);
  for (int ki = 0; ki < 16; ki++) {
    int cur = ki & 1;
    if (ki < 15) {
      GSTAGE((ki + 1) << 6, cur ^ 1);
      asm volatile("s_waitcnt vmcnt(4)" ::: "memory");
    } else {
      asm volatile("s_waitcnt vmcnt(0)" ::: "memory");
    }
    __builtin_amdgcn_s_barrier();
    asm volatile("" ::: "memory");
#pragma unroll
    for (int kk = 0; kk < 2; kk++) {
      bf16x8 af[2], bfr[4];
#pragma unroll
      for (int m = 0; m < 2; m++) {
        int ar = wr * 32 + m * 16 + l15;
        af[m] = *(const bf16x8*)((char*)As[cur] + ar * 128 + ((kk * 64 + l16 * 16) ^ ((ar & 7) << 4)));
      }
#pragma unroll
      for (int n = 0; n < 4; n++) {
        int br = wc * 64 + n * 16 + l15;
        bfr[n] = *(const bf16x8*)((char*)Bs[cur] + br * 128 + ((kk * 64 + l16 * 16) ^ ((br & 7) << 4)));
      }
#pragma unroll
      for (int m = 0; m < 2; m++)
#pragma unroll
        for (int n = 0; n < 4; n++)
          acc[m][n] = __builtin_amdgcn_mfma_f32_16x16x32_bf16(af[m], bfr[n], acc[m][n], 0, 0, 0);
    }
    __builtin_amdgcn_s_barrier();
    asm volatile("" ::: "memory");
  }
#undef GSTAGE
}

// O-projection GEMM with fused residual + LN-statistics epilogue -> bf16 H + row sums
__global__ __launch_bounds__(512) void k_gemm_o(const u16t* __restrict__ A,
                                                const u16t* __restrict__ Wt,
                                                const float* __restrict__ bias,
                                                const float* __restrict__ target,
                                                u16t* __restrict__ Hb,
                                                float* __restrict__ rsums) {
  int bid = blockIdx.y * 8 + blockIdx.x;          // 256 blocks
  int swz = (bid & 7) * 32 + (bid >> 3);          // XCD chunking
  int n0 = (swz & 7) * 128, m0 = (swz >> 3) * 128;
  f32x4 acc[2][4] = {};
  gemm128_acc8(A, Wt, m0, n0, acc);
  int t = threadIdx.x, lane = t & 63, w = t >> 6;
  int l15 = lane & 15, l16 = lane >> 4;
  int wr = w >> 1, wc = w & 1;
  float bb[4];
#pragma unroll
  for (int n = 0; n < 4; n++) bb[n] = bias[n0 + wc * 64 + n * 16 + l15];
#pragma unroll
  for (int m = 0; m < 2; m++) {
#pragma unroll
    for (int r = 0; r < 4; r++) {
      int row = m0 + wr * 32 + m * 16 + l16 * 4 + r;
      float s = 0.f, ss = 0.f;
      float xs[4];
#pragma unroll
      for (int n = 0; n < 4; n++) {
        int col = n0 + wc * 64 + n * 16 + l15;
        float x = acc[m][n][r] + bb[n] + target[((size_t)row << 10) + col];
        xs[n] = x; s += x; ss = fmaf(x, x, ss);
      }
#pragma unroll
      for (int n = 0; n < 4; n++)
        Hb[((size_t)row << 10) + n0 + wc * 64 + n * 16 + l15] = f2bf(xs[n]);
      s += __shfl_xor(s, 1); ss += __shfl_xor(ss, 1);
      s += __shfl_xor(s, 2); ss += __shfl_xor(ss, 2);
      s += __shfl_xor(s, 4); ss += __shfl_xor(ss, 4);
      s += __shfl_xor(s, 8); ss += __shfl_xor(ss, 8);
      if (l15 == 0) {
        atomicAdd(&rsums[row * 2], s);
        atomicAdd(&rsums[row * 2 + 1], ss);
      }
    }
  }
}

// ---------------- LayerNorm finalize: pure normalize from precomputed sums ----------------
__global__ __launch_bounds__(256) void k_out_ln(const u16t* __restrict__ Hb,
                                                const float* __restrict__ rsums,
                                                const float* __restrict__ g,
                                                const float* __restrict__ bb,
                                                float* __restrict__ out) {
  int row = blockIdx.x, t = threadIdx.x;
  u16x4 hx = *reinterpret_cast<const u16x4*>(Hb + ((size_t)row << 10) + t * 4);
  float s = rsums[row * 2], ss = rsums[row * 2 + 1];
  float mu = s * (1.f / 1024.f);
  float var = ss * (1.f / 1024.f) - mu * mu;
  float rsn = rsqrtf(var + 1e-12f);
  f32x4 gv = *reinterpret_cast<const f32x4*>(&g[t * 4]);
  f32x4 bv = *reinterpret_cast<const f32x4*>(&bb[t * 4]);
  f32x4 o;
#pragma unroll
  for (int j = 0; j < 4; j++) o[j] = (bf2f(hx[j]) - mu) * rsn * gv[j] + bv[j];
  *reinterpret_cast<f32x4*>(&out[(size_t)row * 1024 + t * 4]) = o;
}

extern "C" void kernel_launch(void* const* d_in, const int* in_sizes, int n_in,
                              void* d_out, int out_size, void* d_ws, size_t ws_size,
                              hipStream_t stream) {
  const float* target = (const float*)d_in[0];
  const float* source = (const float*)d_in[1];
  const float* value  = (const float*)d_in[2];
  const float* Wq = (const float*)d_in[3];
  const float* bq = (const float*)d_in[4];
  const float* Wk = (const float*)d_in[5];
  const float* bk = (const float*)d_in[6];
  const float* Wv = (const float*)d_in[7];
  const float* bvp = (const float*)d_in[8];
  const float* Wo = (const float*)d_in[9];
  const float* bo = (const float*)d_in[10];
  const float* lng = (const float*)d_in[11];
  const float* lnb = (const float*)d_in[12];
  float* out = (float*)d_out;
  char* ws = (char*)d_ws;
  const size_t MB = 1u << 20;

  // ws layout:
  //  [0,8)   ctxb bf16 [4096][1024]
  //  [16,24) Wt bf16 4x transposed weights
  //  [24,32) qn8 bf16 [4096][1024]
  //  [40,44) knT bf16 [1024][2048]
  //  [44,48) vT  bf16 [1024][2048]
  //  [48,56) Hb bf16 [4096][1024]
  //  [64MB)  Kcol | Vcol | MT    [65MB) rsums
  u16t* ctxb  = (u16t*)ws;
  u16t* Wt    = (u16t*)(ws + 16 * MB);
  u16t* Wot   = Wt + ((size_t)3 << 20);
  u16t* qnb   = (u16t*)(ws + 24 * MB);
  u16t* knT   = (u16t*)(ws + 40 * MB);
  u16t* vTb   = (u16t*)(ws + 44 * MB);
  u16t* Hb    = (u16t*)(ws + 48 * MB);
  float* Kcolf = (float*)(ws + 64 * MB);
  float* Vcolf = Kcolf + 1024;
  u16t* MTb   = (u16t*)(Vcolf + 1024);
  float* rsums = (float*)(ws + 65 * MB);

  k_wtrans4<<<dim3(16, 16, 4), 256, 0, stream>>>(Wq, Wk, Wv, Wo, Wt, Kcolf, rsums);
  k_gemm_qkv<<<dim3(8, 64), 512, 0, stream>>>(target, source, value, Wt, bq, bk, bvp,
                                              qnb, knT, vTb, Kcolf, Vcolf);
  k_ktv<<<dim3(4, 16), 256, 0, stream>>>(knT, vTb, Kcolf, MTb);
  k_ctx<<<dim3(128), 256, 0, stream>>>(qnb, MTb, Vcolf, ctxb);
  k_gemm_o<<<dim3(8, 32), 512, 0, stream>>>(ctxb, Wot, bo, target, Hb, rsums);
  k_out_ln<<<dim3(4096), 256, 0, stream>>>(Hb, rsums, lng, lnb, out);
}

// Round 21
// 85.358 us; speedup vs baseline: 1.9510x; 1.0016x over previous
//
#include <hip/hip_runtime.h>
#include <math.h>

typedef unsigned short u16t;
typedef __attribute__((ext_vector_type(8))) __bf16 bf16x8;
typedef __attribute__((ext_vector_type(4))) float f32x4;
typedef __attribute__((ext_vector_type(16))) float f32x16;
typedef __attribute__((ext_vector_type(4))) unsigned short u16x4;

__device__ __forceinline__ u16t f2bf(float f) {
  union { float f; unsigned u; } v; v.f = f;
  return (u16t)((v.u + 0x7FFFu + ((v.u >> 16) & 1u)) >> 16);
}
__device__ __forceinline__ float bf2f(u16t u) {
  union { unsigned u; float f; } v; v.u = (unsigned)u << 16; return v.f;
}

// async global->LDS, 16B per lane; LDS dest linear (wave-uniform base + lane*16)
__device__ __forceinline__ void gload_lds16(const void* g, void* l) {
  __builtin_amdgcn_global_load_lds(
      (__attribute__((address_space(1))) void*)(uintptr_t)g,
      (__attribute__((address_space(3))) void*)(unsigned)(uintptr_t)l,
      16, 0, 0);
}

__device__ __forceinline__ f32x16 mf32(bf16x8 a, bf16x8 b, f32x16 c) {
  return __builtin_amdgcn_mfma_f32_32x32x16_bf16(a, b, c, 0, 0, 0);
}

// pack 8 f32 (2x f32x4) -> bf16x8 via v_cvt_pk_bf16_f32 (RNE)
__device__ __forceinline__ bf16x8 pk8(f32x4 a, f32x4 b) {
  union { unsigned u[4]; bf16x8 v; } r;
  asm("v_cvt_pk_bf16_f32 %0, %1, %2" : "=v"(r.u[0]) : "v"(a[0]), "v"(a[1]));
  asm("v_cvt_pk_bf16_f32 %0, %1, %2" : "=v"(r.u[1]) : "v"(a[2]), "v"(a[3]));
  asm("v_cvt_pk_bf16_f32 %0, %1, %2" : "=v"(r.u[2]) : "v"(b[0]), "v"(b[1]));
  asm("v_cvt_pk_bf16_f32 %0, %1, %2" : "=v"(r.u[3]) : "v"(b[2]), "v"(b[3]));
  return r.v;
}

// ---------------- fused 4x weight transpose + accumulator zeroing ----------------
__global__ __launch_bounds__(256) void k_wtrans4(const float* __restrict__ Wq,
                                                 const float* __restrict__ Wk,
                                                 const float* __restrict__ Wv,
                                                 const float* __restrict__ Wo,
                                                 u16t* __restrict__ dstAll,
                                                 float* __restrict__ KVcol,
                                                 float* __restrict__ rsums) {
  __shared__ u16t tile[64][68];
  int z = blockIdx.z;
  const float* in = z == 0 ? Wq : z == 1 ? Wk : z == 2 ? Wv : Wo;
  u16t* out = dstAll + ((size_t)z << 20);
  int r0 = blockIdx.y * 64, c0 = blockIdx.x * 64;
  int t = threadIdx.x;
  if (z == 0 && blockIdx.y == 0) {
    int g = blockIdx.x * 256 + t;          // 0..4095
    if (g < 2048) KVcol[g] = 0.f;
    rsums[g] = 0.f;
    rsums[g + 4096] = 0.f;
  }
  int rr = t >> 4, q4 = (t & 15) * 4;
#pragma unroll
  for (int i = 0; i < 4; i++) {
    int r = rr + i * 16;
    f32x4 x = *reinterpret_cast<const f32x4*>(&in[(size_t)(r0 + r) * 1024 + c0 + q4]);
#pragma unroll
    for (int j = 0; j < 4; j++) tile[r][q4 + j] = f2bf(x[j]);
  }
  __syncthreads();
#pragma unroll
  for (int i = 0; i < 4; i++) {
    int c = rr + i * 16;
    u16x4 y;
#pragma unroll
    for (int j = 0; j < 4; j++) y[j] = tile[q4 + j][c];
    *reinterpret_cast<u16x4*>(&out[(size_t)(c0 + c) * 1024 + r0 + q4]) = y;
  }
}

// ---------------- k_ktv: per-head M_h = kn_h^T @ v_h  (stored transposed, bf16) ----
__global__ __launch_bounds__(256) void k_ktv(const u16t* __restrict__ knT,
                                             const u16t* __restrict__ vT,
                                             const float* __restrict__ Kcol,
                                             u16t* __restrict__ MT) {
  __shared__ float sls[4][1024];
  int qd = blockIdx.x, h = blockIdx.y;
  int e1t = qd >> 1, e2t = qd & 1;
  int t = threadIdx.x, lane = t & 63, w = t >> 6;
  int l31 = lane & 31, hi = lane >> 5;
  const u16t* ap = knT + (((size_t)((h << 6) + e1t * 32 + l31)) << 11) + w * 512 + hi * 8;
  const u16t* bp = vT  + (((size_t)((h << 6) + e2t * 32 + l31)) << 11) + w * 512 + hi * 8;
  f32x16 acc = {};
#pragma unroll
  for (int k = 0; k < 32; k++) {
    bf16x8 a = *(const bf16x8*)(ap + k * 16);
    bf16x8 b = *(const bf16x8*)(bp + k * 16);
    acc = mf32(a, b, acc);
  }
#pragma unroll
  for (int r = 0; r < 16; r++) {
    int e1l = (r & 3) + 8 * (r >> 2) + 4 * hi;
    sls[w][e1l * 32 + l31] = acc[r];
  }
  __syncthreads();
#pragma unroll
  for (int i = 0; i < 4; i++) {
    int idx = t * 4 + i;
    int e1 = idx >> 5, e2 = idx & 31;
    float s = sls[0][idx] + sls[1][idx] + sls[2][idx] + sls[3][idx];
    MT[h * 4160 + (e2t * 32 + e2) * 64 + e1t * 32 + e1] = f2bf(s);
  }
  if (qd == 0 && t < 64)
    MT[h * 4160 + 4096 + t] = f2bf(Kcol[(h << 6) + t]);
}

// ---------------- k_ctx: ctx = (qn8 @ M + Vcol) / (2048 + qn8.Kcol) -> bf16 ----
__global__ __launch_bounds__(256) void k_ctx(const u16t* __restrict__ qn8,
                                             const u16t* __restrict__ MT,
                                             const float* __restrict__ Vcol,
                                             u16t* __restrict__ ctx) {
  int rt = blockIdx.x;
  int t = threadIdx.x, lane = t & 63, w = t >> 6;
  int l31 = lane & 31, hi = lane >> 5;
  int rowb = rt * 32;
  const u16t* qbase = qn8 + (((size_t)(rowb + l31)) << 10) + hi * 8;
  const f32x16 fz = {};
#pragma unroll
  for (int hh = 0; hh < 4; hh++) {
    int h = w * 4 + hh;
    const u16t* mbase = MT + h * 4160;
    bf16x8 af[4], kf[4];
#pragma unroll
    for (int ks = 0; ks < 4; ks++) {
      af[ks] = *(const bf16x8*)(qbase + (h << 6) + ks * 16);
      kf[ks] = *(const bf16x8*)(mbase + 4096 + ks * 16 + hi * 8);
    }
    f32x16 a0, a1, rd;
#pragma unroll
    for (int ks = 0; ks < 4; ks++) {
      bf16x8 b0 = *(const bf16x8*)(mbase + l31 * 64 + ks * 16 + hi * 8);
      bf16x8 b1 = *(const bf16x8*)(mbase + (32 + l31) * 64 + ks * 16 + hi * 8);
      a0 = mf32(af[ks], b0, ks ? a0 : fz);
      a1 = mf32(af[ks], b1, ks ? a1 : fz);
      rd = mf32(af[ks], kf[ks], ks ? rd : fz);
    }
    float vc0 = Vcol[(h << 6) + l31];
    float vc1 = Vcol[(h << 6) + 32 + l31];
#pragma unroll
    for (int r = 0; r < 16; r++) {
      int row = rowb + (r & 3) + 8 * (r >> 2) + 4 * hi;
      float ri = 1.f / (2048.f + rd[r]);
      u16t* cp = ctx + (((size_t)row) << 10) + (h << 6) + l31;
      cp[0]  = f2bf((a0[r] + vc0) * ri);
      cp[32] = f2bf((a1[r] + vc1) * ri);
    }
  }
}

// ---------------- QKV GEMM v4.1: f32 A DMA'd LDS (BK=32), B bf16 DMA, B macro-row swz ----
// B LDS layout: 64 macro-rows x 128B; logical row br at mr=br>>1, half hi=br&1;
// chunk j16 stored at mr*128 + hi*64 + (j16 ^ ((mr&3)<<4)) -> 8 slots/16 lanes = 2-way free.
__global__ __launch_bounds__(512) void k_gemm_qkv(const float* __restrict__ target,
                                                  const float* __restrict__ source,
                                                  const float* __restrict__ value,
                                                  const u16t* __restrict__ Wt,
                                                  const float* __restrict__ b0,
                                                  const float* __restrict__ b1,
                                                  const float* __restrict__ b2,
                                                  u16t* __restrict__ qn8,
                                                  u16t* __restrict__ knT,
                                                  u16t* __restrict__ vT,
                                                  float* __restrict__ Kcol,
                                                  float* __restrict__ Vcol) {
  __shared__ __align__(16) char AsB[2][16384];
  __shared__ __align__(16) char BsB[2][8192];
  int bid = blockIdx.y * 8 + blockIdx.x;          // 512 blocks
  int swz = (bid & 7) * 64 + (bid >> 3);          // bijective XCD chunking
  int n0 = (swz & 7) * 128, m0 = (swz >> 3) * 128;
  int seg = (m0 >= 6144) ? 2 : (m0 >= 4096) ? 1 : 0;
  const float* bias = (seg == 0) ? b0 : (seg == 1) ? b1 : b2;
  const float* Af = (seg == 0) ? target : (seg == 1) ? source : value;
  int mloc = m0 - ((seg == 0) ? 0 : (seg == 1) ? 4096 : 6144);
  const u16t* Bseg = Wt + ((size_t)seg << 20);

  int t = threadIdx.x, lane = t & 63, w = t >> 6;
  int l15 = lane & 15, l16 = lane >> 4;
  int wr = w >> 1, wc = w & 1;
  f32x4 acc[2][4] = {};

  // A stage: chunks ic = t, t+512; row = ic>>3, c = ic&7; pre-swizzled source
  int ar0 = t >> 3, ac0 = t & 7;
  int ae0 = ((ac0 ^ (ar0 & 7)) << 2);             // element offset (f32)
  // B stage (macro-row layout): t = mrq*8 + sq
  int mrq = t >> 3, sq = t & 7;
  int bbr = mrq * 2 + (sq >> 2);                  // logical row
  int bel = ((sq & 3) ^ (mrq & 3)) << 3;          // element offset (bf16)

#define QSTG(KT, NB) do {                                                        \
    gload_lds16(Af + (((size_t)(mloc + ar0)) << 10) + (KT) + ae0,                \
                AsB[NB] + t * 16);                                               \
    gload_lds16(Af + (((size_t)(mloc + 64 + ar0)) << 10) + (KT) + ae0,           \
                AsB[NB] + 8192 + t * 16);                                        \
    gload_lds16(Bseg + (((size_t)(n0 + bbr)) << 10) + (KT) + bel,                \
                BsB[NB] + t * 16);                                               \
  } while (0)

  QSTG(0, 0);
  for (int ki = 0; ki < 32; ki++) {
    int cur = ki & 1;
    if (ki < 31) {
      QSTG((ki + 1) << 5, cur ^ 1);
      asm volatile("s_waitcnt vmcnt(3)" ::: "memory");
    } else {
      asm volatile("s_waitcnt vmcnt(0)" ::: "memory");
    }
    __builtin_amdgcn_s_barrier();
    asm volatile("" ::: "memory");
    const char* ab = AsB[cur];
    const char* bb = BsB[cur];
    bf16x8 af[2], bfr[4];
#pragma unroll
    for (int m = 0; m < 2; m++) {
      int ar = wr * 32 + m * 16 + l15;
      int sw = (ar & 7) << 4;
      int base = ar * 128 + l16 * 32;
      f32x4 c0 = *(const f32x4*)(ab + (base ^ sw));
      f32x4 c1 = *(const f32x4*)(ab + ((base + 16) ^ sw));
      af[m] = pk8(c0, c1);
    }
#pragma unroll
    for (int n = 0; n < 4; n++) {
      int br = wc * 64 + n * 16 + l15;
      int mr = br >> 1;
      bfr[n] = *(const bf16x8*)(bb + mr * 128 + (br & 1) * 64 + ((l16 * 16) ^ ((mr & 3) << 4)));
    }
#pragma unroll
    for (int m = 0; m < 2; m++)
#pragma unroll
      for (int n = 0; n < 4; n++)
        acc[m][n] = __builtin_amdgcn_mfma_f32_16x16x32_bf16(af[m], bfr[n], acc[m][n], 0, 0, 0);
    __builtin_amdgcn_s_barrier();
    asm volatile("" ::: "memory");
  }
#undef QSTG

  float bb4[4];
#pragma unroll
  for (int n = 0; n < 4; n++) bb4[n] = bias[n0 + wc * 64 + n * 16 + l15];

  if (seg == 0) {
#pragma unroll
    for (int m = 0; m < 2; m++) {
#pragma unroll
      for (int r = 0; r < 4; r++) {
        float e[4]; float ss = 0.f;
#pragma unroll
        for (int n = 0; n < 4; n++) {
          float x = acc[m][n][r] + bb4[n];
          e[n] = x > 0.f ? x : (__expf(x) - 1.f);
          ss += e[n] * e[n];
        }
        ss += __shfl_xor(ss, 1); ss += __shfl_xor(ss, 2);
        ss += __shfl_xor(ss, 4); ss += __shfl_xor(ss, 8);
        float rinv = rsqrtf(ss) * 0.125f;
        int row = m0 + wr * 32 + m * 16 + l16 * 4 + r;
#pragma unroll
        for (int n = 0; n < 4; n++)
          qn8[((size_t)row << 10) + n0 + wc * 64 + n * 16 + l15] = f2bf(e[n] * rinv);
      }
    }
  } else {
    u16t* outT = (seg == 1) ? knT : vT;
    float* colp = (seg == 1) ? Kcol : Vcol;
    float cs[4] = {0.f, 0.f, 0.f, 0.f};
#pragma unroll
    for (int m = 0; m < 2; m++) {
      u16x4 tv[4];
#pragma unroll
      for (int r = 0; r < 4; r++) {
        float v[4];
        if (seg == 1) {
          float e[4]; float ss = 0.f;
#pragma unroll
          for (int n = 0; n < 4; n++) {
            float x = acc[m][n][r] + bb4[n];
            e[n] = x > 0.f ? x : (__expf(x) - 1.f);
            ss += e[n] * e[n];
          }
          ss += __shfl_xor(ss, 1); ss += __shfl_xor(ss, 2);
          ss += __shfl_xor(ss, 4); ss += __shfl_xor(ss, 8);
          float rinv = rsqrtf(ss);
#pragma unroll
          for (int n = 0; n < 4; n++) v[n] = e[n] * rinv;
        } else {
#pragma unroll
          for (int n = 0; n < 4; n++) v[n] = acc[m][n][r] + bb4[n];
        }
#pragma unroll
        for (int n = 0; n < 4; n++) { tv[n][r] = f2bf(v[n]); cs[n] += v[n]; }
      }
      int rowb = (m0 - ((seg == 1) ? 4096 : 6144)) + wr * 32 + m * 16 + l16 * 4;
#pragma unroll
      for (int n = 0; n < 4; n++) {
        int col = n0 + wc * 64 + n * 16 + l15;
        *reinterpret_cast<u16x4*>(outT + ((size_t)col << 11) + rowb) = tv[n];
      }
    }
#pragma unroll
    for (int n = 0; n < 4; n++) {
      float s = cs[n];
      s += __shfl_xor(s, 16); s += __shfl_xor(s, 32);
      if (l16 == 0) atomicAdd(&colp[n0 + wc * 64 + n * 16 + l15], s);
    }
  }
}

// ---------------- 128x128x(K=1024) MFMA core, 512 threads (R17-proven, bf16 A) ----------
__device__ __forceinline__ void gemm128_acc8(const u16t* __restrict__ A,
                                             const u16t* __restrict__ Bt,
                                             int m0, int n0, f32x4 acc[2][4]) {
  __shared__ __align__(16) u16t As[2][128 * 64];
  __shared__ __align__(16) u16t Bs[2][128 * 64];
  int t = threadIdx.x, lane = t & 63, w = t >> 6;
  int l15 = lane & 15, l16 = lane >> 4;
  int wr = w >> 1, wc = w & 1;
  int srow = t >> 3;                      // 0..63
  int slc = ((t & 7) ^ (srow & 7)) << 3;  // pre-swizzled element offset

#define GSTAGE(KT, NB) do {                                                      \
    _Pragma("unroll")                                                            \
    for (int i = 0; i < 2; i++) {                                                \
      int row_ = srow + i * 64;                                                  \
      int c16_ = (t + i * 512) * 16;                                             \
      gload_lds16(A + ((size_t)(m0 + row_) << 10) + (KT) + slc, (char*)As[NB] + c16_); \
      gload_lds16(Bt + ((size_t)(n0 + row_) << 10) + (KT) + slc, (char*)Bs[NB] + c16_); \
    } } while (0)

  GSTAGE(0, 0);
  for (int ki = 0; ki < 16; ki++) {
    int cur = ki & 1;
    if (ki < 15) {
      GSTAGE((ki + 1) << 6, cur ^ 1);
      asm volatile("s_waitcnt vmcnt(4)" ::: "memory");
    } else {
      asm volatile("s_waitcnt vmcnt(0)" ::: "memory");
    }
    __builtin_amdgcn_s_barrier();
    asm volatile("" ::: "memory");
#pragma unroll
    for (int kk = 0; kk < 2; kk++) {
      bf16x8 af[2], bfr[4];
#pragma unroll
      for (int m = 0; m < 2; m++) {
        int ar = wr * 32 + m * 16 + l15;
        af[m] = *(const bf16x8*)((char*)As[cur] + ar * 128 + ((kk * 64 + l16 * 16) ^ ((ar & 7) << 4)));
      }
#pragma unroll
      for (int n = 0; n < 4; n++) {
        int br = wc * 64 + n * 16 + l15;
        bfr[n] = *(const bf16x8*)((char*)Bs[cur] + br * 128 + ((kk * 64 + l16 * 16) ^ ((br & 7) << 4)));
      }
#pragma unroll
      for (int m = 0; m < 2; m++)
#pragma unroll
        for (int n = 0; n < 4; n++)
          acc[m][n] = __builtin_amdgcn_mfma_f32_16x16x32_bf16(af[m], bfr[n], acc[m][n], 0, 0, 0);
    }
    __builtin_amdgcn_s_barrier();
    asm volatile("" ::: "memory");
  }
#undef GSTAGE
}

// O-projection GEMM with fused residual + LN-statistics epilogue -> bf16 H + row sums
__global__ __launch_bounds__(512) void k_gemm_o(const u16t* __restrict__ A,
                                                const u16t* __restrict__ Wt,
                                                const float* __restrict__ bias,
                                                const float* __restrict__ target,
                                                u16t* __restrict__ Hb,
                                                float* __restrict__ rsums) {
  int bid = blockIdx.y * 8 + blockIdx.x;          // 256 blocks
  int swz = (bid & 7) * 32 + (bid >> 3);          // XCD chunking
  int n0 = (swz & 7) * 128, m0 = (swz >> 3) * 128;
  f32x4 acc[2][4] = {};
  gemm128_acc8(A, Wt, m0, n0, acc);
  int t = threadIdx.x, lane = t & 63, w = t >> 6;
  int l15 = lane & 15, l16 = lane >> 4;
  int wr = w >> 1, wc = w & 1;
  float bb[4];
#pragma unroll
  for (int n = 0; n < 4; n++) bb[n] = bias[n0 + wc * 64 + n * 16 + l15];
#pragma unroll
  for (int m = 0; m < 2; m++) {
#pragma unroll
    for (int r = 0; r < 4; r++) {
      int row = m0 + wr * 32 + m * 16 + l16 * 4 + r;
      float s = 0.f, ss = 0.f;
      float xs[4];
#pragma unroll
      for (int n = 0; n < 4; n++) {
        int col = n0 + wc * 64 + n * 16 + l15;
        float x = acc[m][n][r] + bb[n] + target[((size_t)row << 10) + col];
        xs[n] = x; s += x; ss = fmaf(x, x, ss);
      }
#pragma unroll
      for (int n = 0; n < 4; n++)
        Hb[((size_t)row << 10) + n0 + wc * 64 + n * 16 + l15] = f2bf(xs[n]);
      s += __shfl_xor(s, 1); ss += __shfl_xor(ss, 1);
      s += __shfl_xor(s, 2); ss += __shfl_xor(ss, 2);
      s += __shfl_xor(s, 4); ss += __shfl_xor(ss, 4);
      s += __shfl_xor(s, 8); ss += __shfl_xor(ss, 8);
      if (l15 == 0) {
        atomicAdd(&rsums[row * 2], s);
        atomicAdd(&rsums[row * 2 + 1], ss);
      }
    }
  }
}

// ---------------- LayerNorm finalize: pure normalize from precomputed sums ----------------
__global__ __launch_bounds__(256) void k_out_ln(const u16t* __restrict__ Hb,
                                                const float* __restrict__ rsums,
                                                const float* __restrict__ g,
                                                const float* __restrict__ bb,
                                                float* __restrict__ out) {
  int row = blockIdx.x, t = threadIdx.x;
  u16x4 hx = *reinterpret_cast<const u16x4*>(Hb + ((size_t)row << 10) + t * 4);
  float s = rsums[row * 2], ss = rsums[row * 2 + 1];
  float mu = s * (1.f / 1024.f);
  float var = ss * (1.f / 1024.f) - mu * mu;
  float rsn = rsqrtf(var + 1e-12f);
  f32x4 gv = *reinterpret_cast<const f32x4*>(&g[t * 4]);
  f32x4 bv = *reinterpret_cast<const f32x4*>(&bb[t * 4]);
  f32x4 o;
#pragma unroll
  for (int j = 0; j < 4; j++) o[j] = (bf2f(hx[j]) - mu) * rsn * gv[j] + bv[j];
  *reinterpret_cast<f32x4*>(&out[(size_t)row * 1024 + t * 4]) = o;
}

extern "C" void kernel_launch(void* const* d_in, const int* in_sizes, int n_in,
                              void* d_out, int out_size, void* d_ws, size_t ws_size,
                              hipStream_t stream) {
  const float* target = (const float*)d_in[0];
  const float* source = (const float*)d_in[1];
  const float* value  = (const float*)d_in[2];
  const float* Wq = (const float*)d_in[3];
  const float* bq = (const float*)d_in[4];
  const float* Wk = (const float*)d_in[5];
  const float* bk = (const float*)d_in[6];
  const float* Wv = (const float*)d_in[7];
  const float* bvp = (const float*)d_in[8];
  const float* Wo = (const float*)d_in[9];
  const float* bo = (const float*)d_in[10];
  const float* lng = (const float*)d_in[11];
  const float* lnb = (const float*)d_in[12];
  float* out = (float*)d_out;
  char* ws = (char*)d_ws;
  const size_t MB = 1u << 20;

  u16t* ctxb  = (u16t*)ws;                        // [0,8) bf16 [4096][1024]
  u16t* Wt    = (u16t*)(ws + 16 * MB);
  u16t* Wot   = Wt + ((size_t)3 << 20);
  u16t* qnb   = (u16t*)(ws + 24 * MB);
  u16t* knT   = (u16t*)(ws + 40 * MB);
  u16t* vTb   = (u16t*)(ws + 44 * MB);
  u16t* Hb    = (u16t*)(ws + 48 * MB);
  float* Kcolf = (float*)(ws + 64 * MB);
  float* Vcolf = Kcolf + 1024;
  u16t* MTb   = (u16t*)(Vcolf + 1024);
  float* rsums = (float*)(ws + 65 * MB);

  k_wtrans4<<<dim3(16, 16, 4), 256, 0, stream>>>(Wq, Wk, Wv, Wo, Wt, Kcolf, rsums);
  k_gemm_qkv<<<dim3(8, 64), 512, 0, stream>>>(target, source, value, Wt, bq, bk, bvp,
                                              qnb, knT, vTb, Kcolf, Vcolf);
  k_ktv<<<dim3(4, 16), 256, 0, stream>>>(knT, vTb, Kcolf, MTb);
  k_ctx<<<dim3(128), 256, 0, stream>>>(qnb, MTb, Vcolf, ctxb);
  k_gemm_o<<<dim3(8, 32), 512, 0, stream>>>(ctxb, Wot, bo, target, Hb, rsums);
  k_out_ln<<<dim3(4096), 256, 0, stream>>>(Hb, rsums, lng, lnb, out);
}

// Round 22
// 84.168 us; speedup vs baseline: 1.9786x; 1.0141x over previous
//
#include <hip/hip_runtime.h>
#include <math.h>

typedef unsigned short u16t;
typedef __attribute__((ext_vector_type(8))) __bf16 bf16x8;
typedef __attribute__((ext_vector_type(4))) float f32x4;
typedef __attribute__((ext_vector_type(16))) float f32x16;
typedef __attribute__((ext_vector_type(4))) unsigned short u16x4;

__device__ __forceinline__ u16t f2bf(float f) {
  union { float f; unsigned u; } v; v.f = f;
  return (u16t)((v.u + 0x7FFFu + ((v.u >> 16) & 1u)) >> 16);
}
__device__ __forceinline__ float bf2f(u16t u) {
  union { unsigned u; float f; } v; v.u = (unsigned)u << 16; return v.f;
}

// async global->LDS, 16B per lane; LDS dest linear (wave-uniform base + lane*16)
__device__ __forceinline__ void gload_lds16(const void* g, void* l) {
  __builtin_amdgcn_global_load_lds(
      (__attribute__((address_space(1))) void*)(uintptr_t)g,
      (__attribute__((address_space(3))) void*)(unsigned)(uintptr_t)l,
      16, 0, 0);
}

__device__ __forceinline__ f32x16 mf32(bf16x8 a, bf16x8 b, f32x16 c) {
  return __builtin_amdgcn_mfma_f32_32x32x16_bf16(a, b, c, 0, 0, 0);
}

// pack 8 f32 (2x f32x4) -> bf16x8 via v_cvt_pk_bf16_f32 (RNE)
__device__ __forceinline__ bf16x8 pk8(f32x4 a, f32x4 b) {
  union { unsigned u[4]; bf16x8 v; } r;
  asm("v_cvt_pk_bf16_f32 %0, %1, %2" : "=v"(r.u[0]) : "v"(a[0]), "v"(a[1]));
  asm("v_cvt_pk_bf16_f32 %0, %1, %2" : "=v"(r.u[1]) : "v"(a[2]), "v"(a[3]));
  asm("v_cvt_pk_bf16_f32 %0, %1, %2" : "=v"(r.u[2]) : "v"(b[0]), "v"(b[1]));
  asm("v_cvt_pk_bf16_f32 %0, %1, %2" : "=v"(r.u[3]) : "v"(b[2]), "v"(b[3]));
  return r.v;
}

// ---------------- fused 4x weight transpose + accumulator zeroing ----------------
__global__ __launch_bounds__(256) void k_wtrans4(const float* __restrict__ Wq,
                                                 const float* __restrict__ Wk,
                                                 const float* __restrict__ Wv,
                                                 const float* __restrict__ Wo,
                                                 u16t* __restrict__ dstAll,
                                                 float* __restrict__ KVcol,
                                                 float* __restrict__ rsums) {
  __shared__ u16t tile[64][68];
  int z = blockIdx.z;
  const float* in = z == 0 ? Wq : z == 1 ? Wk : z == 2 ? Wv : Wo;
  u16t* out = dstAll + ((size_t)z << 20);
  int r0 = blockIdx.y * 64, c0 = blockIdx.x * 64;
  int t = threadIdx.x;
  if (z == 0 && blockIdx.y == 0) {
    int g = blockIdx.x * 256 + t;          // 0..4095
    if (g < 2048) KVcol[g] = 0.f;
    rsums[g] = 0.f;
    rsums[g + 4096] = 0.f;
  }
  int rr = t >> 4, q4 = (t & 15) * 4;
#pragma unroll
  for (int i = 0; i < 4; i++) {
    int r = rr + i * 16;
    f32x4 x = *reinterpret_cast<const f32x4*>(&in[(size_t)(r0 + r) * 1024 + c0 + q4]);
#pragma unroll
    for (int j = 0; j < 4; j++) tile[r][q4 + j] = f2bf(x[j]);
  }
  __syncthreads();
#pragma unroll
  for (int i = 0; i < 4; i++) {
    int c = rr + i * 16;
    u16x4 y;
#pragma unroll
    for (int j = 0; j < 4; j++) y[j] = tile[q4 + j][c];
    *reinterpret_cast<u16x4*>(&out[(size_t)(c0 + c) * 1024 + r0 + q4]) = y;
  }
}

// ---------------- k_ktv: per-head M_h = kn_h^T @ v_h  (stored transposed, bf16) ----
__global__ __launch_bounds__(256) void k_ktv(const u16t* __restrict__ knT,
                                             const u16t* __restrict__ vT,
                                             const float* __restrict__ Kcol,
                                             u16t* __restrict__ MT) {
  __shared__ float sls[4][1024];
  int qd = blockIdx.x, h = blockIdx.y;
  int e1t = qd >> 1, e2t = qd & 1;
  int t = threadIdx.x, lane = t & 63, w = t >> 6;
  int l31 = lane & 31, hi = lane >> 5;
  const u16t* ap = knT + (((size_t)((h << 6) + e1t * 32 + l31)) << 11) + w * 512 + hi * 8;
  const u16t* bp = vT  + (((size_t)((h << 6) + e2t * 32 + l31)) << 11) + w * 512 + hi * 8;
  f32x16 acc = {};
#pragma unroll
  for (int k = 0; k < 32; k++) {
    bf16x8 a = *(const bf16x8*)(ap + k * 16);
    bf16x8 b = *(const bf16x8*)(bp + k * 16);
    acc = mf32(a, b, acc);
  }
#pragma unroll
  for (int r = 0; r < 16; r++) {
    int e1l = (r & 3) + 8 * (r >> 2) + 4 * hi;
    sls[w][e1l * 32 + l31] = acc[r];
  }
  __syncthreads();
#pragma unroll
  for (int i = 0; i < 4; i++) {
    int idx = t * 4 + i;
    int e1 = idx >> 5, e2 = idx & 31;
    float s = sls[0][idx] + sls[1][idx] + sls[2][idx] + sls[3][idx];
    MT[h * 4160 + (e2t * 32 + e2) * 64 + e1t * 32 + e1] = f2bf(s);
  }
  if (qd == 0 && t < 64)
    MT[h * 4160 + 4096 + t] = f2bf(Kcol[(h << 6) + t]);
}

// ---------------- k_ctx: ctx = (qn8 @ M + Vcol) / (2048 + qn8.Kcol) -> bf16 ----
__global__ __launch_bounds__(256) void k_ctx(const u16t* __restrict__ qn8,
                                             const u16t* __restrict__ MT,
                                             const float* __restrict__ Vcol,
                                             u16t* __restrict__ ctx) {
  int rt = blockIdx.x;
  int t = threadIdx.x, lane = t & 63, w = t >> 6;
  int l31 = lane & 31, hi = lane >> 5;
  int rowb = rt * 32;
  const u16t* qbase = qn8 + (((size_t)(rowb + l31)) << 10) + hi * 8;
  const f32x16 fz = {};
#pragma unroll
  for (int hh = 0; hh < 4; hh++) {
    int h = w * 4 + hh;
    const u16t* mbase = MT + h * 4160;
    bf16x8 af[4], kf[4];
#pragma unroll
    for (int ks = 0; ks < 4; ks++) {
      af[ks] = *(const bf16x8*)(qbase + (h << 6) + ks * 16);
      kf[ks] = *(const bf16x8*)(mbase + 4096 + ks * 16 + hi * 8);
    }
    f32x16 a0, a1, rd;
#pragma unroll
    for (int ks = 0; ks < 4; ks++) {
      bf16x8 b0 = *(const bf16x8*)(mbase + l31 * 64 + ks * 16 + hi * 8);
      bf16x8 b1 = *(const bf16x8*)(mbase + (32 + l31) * 64 + ks * 16 + hi * 8);
      a0 = mf32(af[ks], b0, ks ? a0 : fz);
      a1 = mf32(af[ks], b1, ks ? a1 : fz);
      rd = mf32(af[ks], kf[ks], ks ? rd : fz);
    }
    float vc0 = Vcol[(h << 6) + l31];
    float vc1 = Vcol[(h << 6) + 32 + l31];
#pragma unroll
    for (int r = 0; r < 16; r++) {
      int row = rowb + (r & 3) + 8 * (r >> 2) + 4 * hi;
      float ri = 1.f / (2048.f + rd[r]);
      u16t* cp = ctx + (((size_t)row) << 10) + (h << 6) + l31;
      cp[0]  = f2bf((a0[r] + vc0) * ri);
      cp[32] = f2bf((a1[r] + vc1) * ri);
    }
  }
}

// ---------------- QKV GEMM v5: f32 A + bf16 B, 3-buffer single-barrier pipeline ----
// BK=32, 32 iters. Per iter: vmcnt(3) [tile ki ready] -> barrier -> MFMA(buf ki%3)
// -> issue DMA tile ki+2 into buf (ki+2)%3. One barrier/iter; prefetch spans a full iter.
// LDS: A 3x16KB + B 3x8KB = 72KB (2 blocks/CU, grid-fixed).
__global__ __launch_bounds__(512) void k_gemm_qkv(const float* __restrict__ target,
                                                  const float* __restrict__ source,
                                                  const float* __restrict__ value,
                                                  const u16t* __restrict__ Wt,
                                                  const float* __restrict__ b0,
                                                  const float* __restrict__ b1,
                                                  const float* __restrict__ b2,
                                                  u16t* __restrict__ qn8,
                                                  u16t* __restrict__ knT,
                                                  u16t* __restrict__ vT,
                                                  float* __restrict__ Kcol,
                                                  float* __restrict__ Vcol) {
  __shared__ __align__(16) char AsB[3][16384];
  __shared__ __align__(16) char BsB[3][8192];
  int bid = blockIdx.y * 8 + blockIdx.x;          // 512 blocks
  int swz = (bid & 7) * 64 + (bid >> 3);          // bijective XCD chunking
  int n0 = (swz & 7) * 128, m0 = (swz >> 3) * 128;
  int seg = (m0 >= 6144) ? 2 : (m0 >= 4096) ? 1 : 0;
  const float* bias = (seg == 0) ? b0 : (seg == 1) ? b1 : b2;
  const float* Af = (seg == 0) ? target : (seg == 1) ? source : value;
  int mloc = m0 - ((seg == 0) ? 0 : (seg == 1) ? 4096 : 6144);
  const u16t* Bseg = Wt + ((size_t)seg << 20);

  int t = threadIdx.x, lane = t & 63, w = t >> 6;
  int l15 = lane & 15, l16 = lane >> 4;
  int wr = w >> 1, wc = w & 1;
  f32x4 acc[2][4] = {};

  // A stage: chunks ic = t, t+512; row = ic>>3, c = ic&7; pre-swizzled source
  int ar0 = t >> 3, ac0 = t & 7;
  int ae0 = ((ac0 ^ (ar0 & 7)) << 2);             // element offset (f32)
  // B stage (macro-row layout): t = mrq*8 + sq
  int mrq = t >> 3, sq = t & 7;
  int bbr = mrq * 2 + (sq >> 2);                  // logical row
  int bel = ((sq & 3) ^ (mrq & 3)) << 3;          // element offset (bf16)

#define QSTG(KT, NB) do {                                                        \
    gload_lds16(Af + (((size_t)(mloc + ar0)) << 10) + (KT) + ae0,                \
                AsB[NB] + t * 16);                                               \
    gload_lds16(Af + (((size_t)(mloc + 64 + ar0)) << 10) + (KT) + ae0,           \
                AsB[NB] + 8192 + t * 16);                                        \
    gload_lds16(Bseg + (((size_t)(n0 + bbr)) << 10) + (KT) + bel,                \
                BsB[NB] + t * 16);                                               \
  } while (0)

  QSTG(0, 0);
  QSTG(32, 1);
  for (int ki = 0; ki < 32; ki++) {
    int cur = ki % 3;
    if (ki < 31) asm volatile("s_waitcnt vmcnt(3)" ::: "memory");
    else         asm volatile("s_waitcnt vmcnt(0)" ::: "memory");
    __builtin_amdgcn_s_barrier();
    asm volatile("" ::: "memory");
    const char* ab = AsB[cur];
    const char* bb = BsB[cur];
    bf16x8 af[2], bfr[4];
#pragma unroll
    for (int m = 0; m < 2; m++) {
      int ar = wr * 32 + m * 16 + l15;
      int sw = (ar & 7) << 4;
      int base = ar * 128 + l16 * 32;
      f32x4 c0 = *(const f32x4*)(ab + (base ^ sw));
      f32x4 c1 = *(const f32x4*)(ab + ((base + 16) ^ sw));
      af[m] = pk8(c0, c1);
    }
#pragma unroll
    for (int n = 0; n < 4; n++) {
      int br = wc * 64 + n * 16 + l15;
      int mr = br >> 1;
      bfr[n] = *(const bf16x8*)(bb + mr * 128 + (br & 1) * 64 + ((l16 * 16) ^ ((mr & 3) << 4)));
    }
#pragma unroll
    for (int m = 0; m < 2; m++)
#pragma unroll
      for (int n = 0; n < 4; n++)
        acc[m][n] = __builtin_amdgcn_mfma_f32_16x16x32_bf16(af[m], bfr[n], acc[m][n], 0, 0, 0);
    if (ki + 2 < 32) QSTG((ki + 2) << 5, (ki + 2) % 3);
  }
#undef QSTG

  float bb4[4];
#pragma unroll
  for (int n = 0; n < 4; n++) bb4[n] = bias[n0 + wc * 64 + n * 16 + l15];

  if (seg == 0) {
#pragma unroll
    for (int m = 0; m < 2; m++) {
#pragma unroll
      for (int r = 0; r < 4; r++) {
        float e[4]; float ss = 0.f;
#pragma unroll
        for (int n = 0; n < 4; n++) {
          float x = acc[m][n][r] + bb4[n];
          e[n] = x > 0.f ? x : (__expf(x) - 1.f);
          ss += e[n] * e[n];
        }
        ss += __shfl_xor(ss, 1); ss += __shfl_xor(ss, 2);
        ss += __shfl_xor(ss, 4); ss += __shfl_xor(ss, 8);
        float rinv = rsqrtf(ss) * 0.125f;
        int row = m0 + wr * 32 + m * 16 + l16 * 4 + r;
#pragma unroll
        for (int n = 0; n < 4; n++)
          qn8[((size_t)row << 10) + n0 + wc * 64 + n * 16 + l15] = f2bf(e[n] * rinv);
      }
    }
  } else {
    u16t* outT = (seg == 1) ? knT : vT;
    float* colp = (seg == 1) ? Kcol : Vcol;
    float cs[4] = {0.f, 0.f, 0.f, 0.f};
#pragma unroll
    for (int m = 0; m < 2; m++) {
      u16x4 tv[4];
#pragma unroll
      for (int r = 0; r < 4; r++) {
        float v[4];
        if (seg == 1) {
          float e[4]; float ss = 0.f;
#pragma unroll
          for (int n = 0; n < 4; n++) {
            float x = acc[m][n][r] + bb4[n];
            e[n] = x > 0.f ? x : (__expf(x) - 1.f);
            ss += e[n] * e[n];
          }
          ss += __shfl_xor(ss, 1); ss += __shfl_xor(ss, 2);
          ss += __shfl_xor(ss, 4); ss += __shfl_xor(ss, 8);
          float rinv = rsqrtf(ss);
#pragma unroll
          for (int n = 0; n < 4; n++) v[n] = e[n] * rinv;
        } else {
#pragma unroll
          for (int n = 0; n < 4; n++) v[n] = acc[m][n][r] + bb4[n];
        }
#pragma unroll
        for (int n = 0; n < 4; n++) { tv[n][r] = f2bf(v[n]); cs[n] += v[n]; }
      }
      int rowb = (m0 - ((seg == 1) ? 4096 : 6144)) + wr * 32 + m * 16 + l16 * 4;
#pragma unroll
      for (int n = 0; n < 4; n++) {
        int col = n0 + wc * 64 + n * 16 + l15;
        *reinterpret_cast<u16x4*>(outT + ((size_t)col << 11) + rowb) = tv[n];
      }
    }
#pragma unroll
    for (int n = 0; n < 4; n++) {
      float s = cs[n];
      s += __shfl_xor(s, 16); s += __shfl_xor(s, 32);
      if (l16 == 0) atomicAdd(&colp[n0 + wc * 64 + n * 16 + l15], s);
    }
  }
}

// ---------------- 128x128x(K=1024) MFMA core, 512 threads (R17-proven, bf16 A) ----------
__device__ __forceinline__ void gemm128_acc8(const u16t* __restrict__ A,
                                             const u16t* __restrict__ Bt,
                                             int m0, int n0, f32x4 acc[2][4]) {
  __shared__ __align__(16) u16t As[2][128 * 64];
  __shared__ __align__(16) u16t Bs[2][128 * 64];
  int t = threadIdx.x, lane = t & 63, w = t >> 6;
  int l15 = lane & 15, l16 = lane >> 4;
  int wr = w >> 1, wc = w & 1;
  int srow = t >> 3;                      // 0..63
  int slc = ((t & 7) ^ (srow & 7)) << 3;  // pre-swizzled element offset

#define GSTAGE(KT, NB) do {                                                      \
    _Pragma("unroll")                                                            \
    for (int i = 0; i < 2; i++) {                                                \
      int row_ = srow + i * 64;                                                  \
      int c16_ = (t + i * 512) * 16;                                             \
      gload_lds16(A + ((size_t)(m0 + row_) << 10) + (KT) + slc, (char*)As[NB] + c16_); \
      gload_lds16(Bt + ((size_t)(n0 + row_) << 10) + (KT) + slc, (char*)Bs[NB] + c16_); \
    } } while (0)

  GSTAGE(0, 0);
  for (int ki = 0; ki < 16; ki++) {
    int cur = ki & 1;
    if (ki < 15) {
      GSTAGE((ki + 1) << 6, cur ^ 1);
      asm volatile("s_waitcnt vmcnt(4)" ::: "memory");
    } else {
      asm volatile("s_waitcnt vmcnt(0)" ::: "memory");
    }
    __builtin_amdgcn_s_barrier();
    asm volatile("" ::: "memory");
#pragma unroll
    for (int kk = 0; kk < 2; kk++) {
      bf16x8 af[2], bfr[4];
#pragma unroll
      for (int m = 0; m < 2; m++) {
        int ar = wr * 32 + m * 16 + l15;
        af[m] = *(const bf16x8*)((char*)As[cur] + ar * 128 + ((kk * 64 + l16 * 16) ^ ((ar & 7) << 4)));
      }
#pragma unroll
      for (int n = 0; n < 4; n++) {
        int br = wc * 64 + n * 16 + l15;
        bfr[n] = *(const bf16x8*)((char*)Bs[cur] + br * 128 + ((kk * 64 + l16 * 16) ^ ((br & 7) << 4)));
      }
#pragma unroll
      for (int m = 0; m < 2; m++)
#pragma unroll
        for (int n = 0; n < 4; n++)
          acc[m][n] = __builtin_amdgcn_mfma_f32_16x16x32_bf16(af[m], bfr[n], acc[m][n], 0, 0, 0);
    }
    __builtin_amdgcn_s_barrier();
    asm volatile("" ::: "memory");
  }
#undef GSTAGE
}

// O-projection GEMM with fused residual + LN-statistics epilogue -> bf16 H + row sums
__global__ __launch_bounds__(512) void k_gemm_o(const u16t* __restrict__ A,
                                                const u16t* __restrict__ Wt,
                                                const float* __restrict__ bias,
                                                const float* __restrict__ target,
                                                u16t* __restrict__ Hb,
                                                float* __restrict__ rsums) {
  int bid = blockIdx.y * 8 + blockIdx.x;          // 256 blocks
  int swz = (bid & 7) * 32 + (bid >> 3);          // XCD chunking
  int n0 = (swz & 7) * 128, m0 = (swz >> 3) * 128;
  f32x4 acc[2][4] = {};
  gemm128_acc8(A, Wt, m0, n0, acc);
  int t = threadIdx.x, lane = t & 63, w = t >> 6;
  int l15 = lane & 15, l16 = lane >> 4;
  int wr = w >> 1, wc = w & 1;
  float bb[4];
#pragma unroll
  for (int n = 0; n < 4; n++) bb[n] = bias[n0 + wc * 64 + n * 16 + l15];
#pragma unroll
  for (int m = 0; m < 2; m++) {
#pragma unroll
    for (int r = 0; r < 4; r++) {
      int row = m0 + wr * 32 + m * 16 + l16 * 4 + r;
      float s = 0.f, ss = 0.f;
      float xs[4];
#pragma unroll
      for (int n = 0; n < 4; n++) {
        int col = n0 + wc * 64 + n * 16 + l15;
        float x = acc[m][n][r] + bb[n] + target[((size_t)row << 10) + col];
        xs[n] = x; s += x; ss = fmaf(x, x, ss);
      }
#pragma unroll
      for (int n = 0; n < 4; n++)
        Hb[((size_t)row << 10) + n0 + wc * 64 + n * 16 + l15] = f2bf(xs[n]);
      s += __shfl_xor(s, 1); ss += __shfl_xor(ss, 1);
      s += __shfl_xor(s, 2); ss += __shfl_xor(ss, 2);
      s += __shfl_xor(s, 4); ss += __shfl_xor(ss, 4);
      s += __shfl_xor(s, 8); ss += __shfl_xor(ss, 8);
      if (l15 == 0) {
        atomicAdd(&rsums[row * 2], s);
        atomicAdd(&rsums[row * 2 + 1], ss);
      }
    }
  }
}

// ---------------- LayerNorm finalize: pure normalize from precomputed sums ----------------
__global__ __launch_bounds__(256) void k_out_ln(const u16t* __restrict__ Hb,
                                                const float* __restrict__ rsums,
                                                const float* __restrict__ g,
                                                const float* __restrict__ bb,
                                                float* __restrict__ out) {
  int row = blockIdx.x, t = threadIdx.x;
  u16x4 hx = *reinterpret_cast<const u16x4*>(Hb + ((size_t)row << 10) + t * 4);
  float s = rsums[row * 2], ss = rsums[row * 2 + 1];
  float mu = s * (1.f / 1024.f);
  float var = ss * (1.f / 1024.f) - mu * mu;
  float rsn = rsqrtf(var + 1e-12f);
  f32x4 gv = *reinterpret_cast<const f32x4*>(&g[t * 4]);
  f32x4 bv = *reinterpret_cast<const f32x4*>(&bb[t * 4]);
  f32x4 o;
#pragma unroll
  for (int j = 0; j < 4; j++) o[j] = (bf2f(hx[j]) - mu) * rsn * gv[j] + bv[j];
  *reinterpret_cast<f32x4*>(&out[(size_t)row * 1024 + t * 4]) = o;
}

extern "C" void kernel_launch(void* const* d_in, const int* in_sizes, int n_in,
                              void* d_out, int out_size, void* d_ws, size_t ws_size,
                              hipStream_t stream) {
  const float* target = (const float*)d_in[0];
  const float* source = (const float*)d_in[1];
  const float* value  = (const float*)d_in[2];
  const float* Wq = (const float*)d_in[3];
  const float* bq = (const float*)d_in[4];
  const float* Wk = (const float*)d_in[5];
  const float* bk = (const float*)d_in[6];
  const float* Wv = (const float*)d_in[7];
  const float* bvp = (const float*)d_in[8];
  const float* Wo = (const float*)d_in[9];
  const float* bo = (const float*)d_in[10];
  const float* lng = (const float*)d_in[11];
  const float* lnb = (const float*)d_in[12];
  float* out = (float*)d_out;
  char* ws = (char*)d_ws;
  const size_t MB = 1u << 20;

  u16t* ctxb  = (u16t*)ws;                        // [0,8) bf16 [4096][1024]
  u16t* Wt    = (u16t*)(ws + 16 * MB);
  u16t* Wot   = Wt + ((size_t)3 << 20);
  u16t* qnb   = (u16t*)(ws + 24 * MB);
  u16t* knT   = (u16t*)(ws + 40 * MB);
  u16t* vTb   = (u16t*)(ws + 44 * MB);
  u16t* Hb    = (u16t*)(ws + 48 * MB);
  float* Kcolf = (float*)(ws + 64 * MB);
  float* Vcolf = Kcolf + 1024;
  u16t* MTb   = (u16t*)(Vcolf + 1024);
  float* rsums = (float*)(ws + 65 * MB);

  k_wtrans4<<<dim3(16, 16, 4), 256, 0, stream>>>(Wq, Wk, Wv, Wo, Wt, Kcolf, rsums);
  k_gemm_qkv<<<dim3(8, 64), 512, 0, stream>>>(target, source, value, Wt, bq, bk, bvp,
                                              qnb, knT, vTb, Kcolf, Vcolf);
  k_ktv<<<dim3(4, 16), 256, 0, stream>>>(knT, vTb, Kcolf, MTb);
  k_ctx<<<dim3(128), 256, 0, stream>>>(qnb, MTb, Vcolf, ctxb);
  k_gemm_o<<<dim3(8, 32), 512, 0, stream>>>(ctxb, Wot, bo, target, Hb, rsums);
  k_out_ln<<<dim3(4096), 256, 0, stream>>>(Hb, rsums, lng, lnb, out);
}